// Round 2
// baseline (898.660 us; speedup 1.0000x reference)
//
#include <hip/hip_runtime.h>
#include <hip/hip_bf16.h>
#include <math.h>

#define NB 32
#define NN 512
#define GIN 192
#define HID 128
#define ATT 384
#define EPSF 1e-11f

// ---------------- row stats: deg -> dinv, mask ----------------
__global__ void k_rowstats(const float* __restrict__ adj, float* __restrict__ dinv,
                           float* __restrict__ mask) {
    int row = blockIdx.x;                 // b*n
    const float* a = adj + (size_t)row * NN;
    int t = threadIdx.x;                  // 64
    float s = 0.f, m = 0.f;
    for (int i = t; i < NN; i += 64) { float v = a[i]; s += v; m = fmaxf(m, v); }
    for (int off = 32; off; off >>= 1) {
        s += __shfl_xor(s, off);
        m = fmaxf(m, __shfl_xor(m, off));
    }
    if (t == 0) {
        dinv[row] = s > 0.f ? 1.0f / sqrtf(s) : 0.f;
        mask[row] = m;
    }
}

__global__ void k_numnodes(const float* __restrict__ mask, float* __restrict__ numn) {
    int b = blockIdx.x, t = threadIdx.x;  // 64
    float s = 0.f;
    for (int i = t; i < NN; i += 64) s += mask[b * NN + i];
    for (int off = 32; off; off >>= 1) s += __shfl_xor(s, off);
    if (t == 0) numn[b] = s;
}

// ---------------- embedding gather ----------------
__global__ void k_gather(const int* __restrict__ n0, const int* __restrict__ n1,
                         const int* __restrict__ n2, const float* __restrict__ e0,
                         const float* __restrict__ e1, const float* __restrict__ e2,
                         float* __restrict__ feats) {
    int tid = blockIdx.x * 256 + threadIdx.x;
    if (tid >= NB * NN * GIN) return;
    int bn = tid / GIN, f = tid - bn * GIN;
    float v;
    if (f < 64)       v = e0[n0[bn] * 64 + f];
    else if (f < 128) v = e1[n1[bn] * 64 + (f - 64)];
    else              v = e2[n2[bn] * 64 + (f - 128)];
    feats[tid] = v;
}

// ---------------- dense GEMM: Y[r,:] = (X[r,:]@W + bias) * dinv[r] ----------------
template <int K>
__global__ __launch_bounds__(256) void k_gemm_dinv(
    const float* __restrict__ X, int ldx, int xoff,
    const float* __restrict__ W, const float* __restrict__ bias,
    const float* __restrict__ dinv, float* __restrict__ Y) {
    __shared__ float xl[16 * K];
    int r0 = blockIdx.x * 16;
    int t = threadIdx.x;
    for (int idx = t; idx < 16 * K; idx += 256) {
        int rr = idx / K, kk = idx - rr * K;
        xl[idx] = X[(size_t)(r0 + rr) * ldx + xoff + kk];
    }
    __syncthreads();
    int col = t & 127, rh = t >> 7;
    float acc[8] = {0.f, 0.f, 0.f, 0.f, 0.f, 0.f, 0.f, 0.f};
    for (int k = 0; k < K; k++) {
        float w = W[k * 128 + col];
#pragma unroll
        for (int q = 0; q < 8; q++) acc[q] += xl[(rh + 2 * q) * K + k] * w;
    }
    float bv = bias[col];
#pragma unroll
    for (int q = 0; q < 8; q++) {
        int r = r0 + rh + 2 * q;
        Y[(size_t)r * 128 + col] = (acc[q] + bv) * dinv[r];
    }
}

// ---------------- adj GEMM: H[b,i,hoff:hoff+128] = tanh(dinv_i * adj[b] @ Y[b]) ----------------
__global__ __launch_bounds__(256) void k_adjmm(const float* __restrict__ adj,
                                               const float* __restrict__ Y,
                                               const float* __restrict__ dinv,
                                               float* __restrict__ H, int hoff) {
    int bb = blockIdx.x >> 4;
    int i0 = (blockIdx.x & 15) * 32;
    __shared__ float at[32 * 32];
    __shared__ float yt[32 * 128];
    int t = threadIdx.x;
    int col = t & 127, rh = t >> 7;
    float acc[16];
#pragma unroll
    for (int q = 0; q < 16; q++) acc[q] = 0.f;
    for (int m0 = 0; m0 < NN; m0 += 32) {
        for (int idx = t; idx < 1024; idx += 256) {
            int rr = idx >> 5, cc = idx & 31;
            at[idx] = adj[((size_t)bb * NN + i0 + rr) * NN + m0 + cc];
        }
        for (int idx = t; idx < 4096; idx += 256) {
            int mm = idx >> 7, c2 = idx & 127;
            yt[idx] = Y[((size_t)bb * NN + m0 + mm) * 128 + c2];
        }
        __syncthreads();
        for (int mm = 0; mm < 32; mm++) {
            float yv = yt[mm * 128 + col];
#pragma unroll
            for (int q = 0; q < 16; q++) acc[q] += at[(rh + 2 * q) * 32 + mm] * yv;
        }
        __syncthreads();
    }
#pragma unroll
    for (int q = 0; q < 16; q++) {
        int i = i0 + rh + 2 * q;
        float v = tanhf(dinv[(size_t)bb * NN + i] * acc[q]);
        H[((size_t)bb * NN + i) * ATT + hoff + col] = v;
    }
}

// ---------------- fused attention: logit[r] = tanh(H[r]@aw1+ab1)@aw2 + ab2 ----------------
__global__ __launch_bounds__(384) void k_attn(const float* __restrict__ H,
                                              const float* __restrict__ aw1,
                                              const float* __restrict__ ab1,
                                              const float* __restrict__ aw2,
                                              const float* __restrict__ ab2,
                                              float* __restrict__ logit) {
    __shared__ float hl[16 * ATT];
    __shared__ float red[6 * 16];
    int r0 = blockIdx.x * 16, t = threadIdx.x;
    for (int idx = t; idx < 16 * ATT; idx += 384) hl[idx] = H[(size_t)r0 * ATT + idx];
    __syncthreads();
    float acc[16];
#pragma unroll
    for (int r = 0; r < 16; r++) acc[r] = 0.f;
    for (int k = 0; k < ATT; k++) {
        float w = aw1[k * ATT + t];
#pragma unroll
        for (int r = 0; r < 16; r++) acc[r] += hl[r * ATT + k] * w;
    }
    float w2 = aw2[t];
    float b1 = ab1[t];
    int lane = t & 63, wv = t >> 6;
    for (int r = 0; r < 16; r++) {
        float p = tanhf(acc[r] + b1) * w2;
        for (int off = 32; off; off >>= 1) p += __shfl_xor(p, off);
        if (lane == 0) red[wv * 16 + r] = p;
    }
    __syncthreads();
    if (t < 16) {
        float s = 0.f;
        for (int w = 0; w < 6; w++) s += red[w * 16 + t];
        logit[r0 + t] = s + ab2[0];
    }
}

// ---------------- attention softmax over n, per batch ----------------
__global__ __launch_bounds__(512) void k_attnsm(float* __restrict__ logit,
                                                const float* __restrict__ mask) {
    __shared__ float red[8];
    __shared__ float red2[8];
    int b = blockIdx.x, t = threadIdx.x;
    float x = mask[b * NN + t] > 0.f ? logit[b * NN + t] : -INFINITY;
    float m = x;
    for (int off = 32; off; off >>= 1) m = fmaxf(m, __shfl_xor(m, off));
    if ((t & 63) == 0) red[t >> 6] = m;
    __syncthreads();
    float gm = red[0];
    for (int i = 1; i < 8; i++) gm = fmaxf(gm, red[i]);
    float e = expf(x - gm);
    float s = e;
    for (int off = 32; off; off >>= 1) s += __shfl_xor(s, off);
    if ((t & 63) == 0) red2[t >> 6] = s;
    __syncthreads();
    float gs = 0.f;
    for (int i = 0; i < 8; i++) gs += red2[i];
    logit[b * NN + t] = e / gs;
}

// ---------------- H *= attn * num_nodes (in place) ----------------
__global__ void k_scaleH(float* __restrict__ H, const float* __restrict__ attn,
                         const float* __restrict__ numn) {
    int tid = blockIdx.x * 256 + threadIdx.x;  // exactly NB*NN*ATT
    int bn = tid / ATT;
    H[tid] *= attn[bn] * numn[bn >> 9];
}

// ---------------- routing softmax over J=16 ----------------
__global__ void k_sm16(const float* __restrict__ bij, float* __restrict__ cij) {
    int gt = blockIdx.x * 256 + threadIdx.x;
    float v = bij[gt];
    float m = v;
    for (int off = 8; off; off >>= 1) m = fmaxf(m, __shfl_xor(m, off, 16));
    float e = expf(v - m), s = e;
    for (int off = 8; off; off >>= 1) s += __shfl_xor(s, off, 16);
    cij[gt] = e / s;
}

// ---------------- Gs[b,c,seg,j,i] = sum_{n in seg} c[b,n,c,j]*Hs[b,n,c,i] ----------------
__global__ __launch_bounds__(256) void k_Gs(const float* __restrict__ cij,
                                            const float* __restrict__ Hs,
                                            float* __restrict__ Gs) {
    int blk = blockIdx.x;  // b*24 + c*4 + seg
    int seg = blk & 3, c = (blk >> 2) % 6, b = blk / 24;
    __shared__ float ct[16 * 16];
    __shared__ float ht[16 * 64];
    int t = threadIdx.x;
    int i = t & 63, j0 = t >> 6;
    float acc[4] = {0.f, 0.f, 0.f, 0.f};
    int n0 = seg * 128;
    for (int nc = 0; nc < 128; nc += 16) {
        {
            int nn = t >> 4, jj = t & 15;
            ct[t] = cij[(((size_t)b * NN + n0 + nc + nn) * 6 + c) * 16 + jj];
        }
        for (int idx = t; idx < 1024; idx += 256) {
            int nn = idx >> 6, ii = idx & 63;
            ht[idx] = Hs[((size_t)b * NN + n0 + nc + nn) * ATT + c * 64 + ii];
        }
        __syncthreads();
        for (int nn = 0; nn < 16; nn++) {
            float hv = ht[nn * 64 + i];
#pragma unroll
            for (int q = 0; q < 4; q++) acc[q] += ct[nn * 16 + j0 * 4 + q] * hv;
        }
        __syncthreads();
    }
#pragma unroll
    for (int q = 0; q < 4; q++) {
        int j = j0 * 4 + q;
        Gs[(((size_t)b * 6 + c) * 4 + seg) * 1024 + j * 64 + i] = acc[q];
    }
}

// ---------------- s,v: v_g[b,j,d] = squash( sum_{c,i} Gsum*Wg / scale ) ----------------
__global__ __launch_bounds__(512) void k_SV(const float* __restrict__ Gs,
                                            const float* __restrict__ Wg,
                                            const float* __restrict__ numn,
                                            float* __restrict__ vg) {
    __shared__ float gsum[6144];
    int b = blockIdx.x, t = threadIdx.x;
    for (int idx = t; idx < 6144; idx += 512) {
        int c = idx >> 10, r = idx & 1023;
        const float* g = Gs + ((size_t)b * 6 + c) * 4096 + r;
        gsum[idx] = g[0] + g[1024] + g[2048] + g[3072];
    }
    __syncthreads();
    int j = t >> 5, d = t & 31;
    float s = 0.f;
    for (int c = 0; c < 6; c++)
        for (int i2 = 0; i2 < 64; i2++)
            s += gsum[(c * 16 + j) * 64 + i2] * Wg[(((size_t)c * 64 + i2) * 16 + j) * 32 + d];
    s /= numn[b];
    float sq = s * s;
    for (int off = 16; off; off >>= 1) sq += __shfl_xor(sq, off, 32);
    float v = (sq / (1.f + sq)) * s / sqrtf(sq + EPSF);
    vg[(size_t)b * 512 + t] = v;
}

// ---------------- Wv[b,c,i,j] = sum_d Wg[c,i,j,d]*v[b,j,d] ----------------
__global__ __launch_bounds__(256) void k_Wv(const float* __restrict__ vg,
                                            const float* __restrict__ Wg,
                                            float* __restrict__ Wv) {
    __shared__ float vl[512];
    int b = blockIdx.x, t = threadIdx.x;
    vl[t] = vg[(size_t)b * 512 + t];
    vl[t + 256] = vg[(size_t)b * 512 + t + 256];
    __syncthreads();
    for (int idx = t; idx < 6144; idx += 256) {
        int c = idx >> 10, r = idx & 1023, i = r >> 4, j = r & 15;
        float a = 0.f;
        const float* w = Wg + (((size_t)c * 64 + i) * 16 + j) * 32;
        for (int d = 0; d < 32; d++) a += w[d] * vl[j * 32 + d];
        Wv[(size_t)b * 6144 + idx] = a;
    }
}

// ---------------- b_ij += sum_i Hs[b,n,c,i]*Wv[b,c,i,j] ----------------
__global__ __launch_bounds__(256) void k_bup(const float* __restrict__ Hs,
                                             const float* __restrict__ Wv,
                                             float* __restrict__ bij) {
    int blk = blockIdx.x;
    int b = blk >> 4;
    int n0 = (blk & 15) * 32;
    __shared__ float wl[6144];
    __shared__ float hl[32 * ATT];
    int t = threadIdx.x;
    for (int idx = t; idx < 6144; idx += 256) wl[idx] = Wv[(size_t)b * 6144 + idx];
    for (int idx = t; idx < 32 * ATT; idx += 256)
        hl[idx] = Hs[((size_t)b * NN + n0) * ATT + idx];
    __syncthreads();
    for (int idx = t; idx < 3072; idx += 256) {
        int nn = idx / 96, r = idx % 96, c = r >> 4, j = r & 15;
        float a = 0.f;
        const float* h = hl + nn * ATT + c * 64;
        const float* w = wl + c * 1024 + j;
#pragma unroll
        for (int i2 = 0; i2 < 64; i2++) a += h[i2] * w[i2 * 16];
        bij[(((size_t)b * NN + n0 + nn) * 6 + c) * 16 + j] += a;
    }
}

// ---------------- second routing + losses, one block per batch ----------------
__global__ __launch_bounds__(256) void k_caps2(
    const float* __restrict__ vg, const float* __restrict__ Wc,
    const int* __restrict__ label, const float* __restrict__ recon_in,
    const float* __restrict__ rw1, const float* __restrict__ rb1,
    const float* __restrict__ rw2, const float* __restrict__ rb2,
    float* __restrict__ out, float* __restrict__ marg, float* __restrict__ reconl) {
    int b = blockIdx.x, t = threadIdx.x;
    __shared__ float vl[512];
    __shared__ float u2[3072];
    __shared__ float b2[96], c2b[96];
    __shared__ float vv[192];
    __shared__ float magl[6];
    __shared__ float cm[32];
    __shared__ float hidl[128];
    __shared__ float red[256];
    vl[t] = vg[(size_t)b * 512 + t];
    vl[t + 256] = vg[(size_t)b * 512 + t + 256];
    if (t < 96) b2[t] = 0.f;
    __syncthreads();
    for (int idx = t; idx < 3072; idx += 256) {
        int c = idx / 192, r = idx - c * 192;  // r = j*32+d
        float a = 0.f;
        const float* w = Wc + (size_t)c * 6144 + r;
        for (int i2 = 0; i2 < 32; i2++) a += vl[c * 32 + i2] * w[i2 * 192];
        u2[idx] = a;
    }
    __syncthreads();
    for (int it = 0; it < 3; it++) {
        if (t < 16) {
            float mx = -INFINITY;
            for (int j = 0; j < 6; j++) mx = fmaxf(mx, b2[t * 6 + j]);
            float e[6], s = 0.f;
            for (int j = 0; j < 6; j++) { e[j] = expf(b2[t * 6 + j] - mx); s += e[j]; }
            for (int j = 0; j < 6; j++) c2b[t * 6 + j] = e[j] / s;
        }
        __syncthreads();
        if (t < 192) {
            int j = t >> 5, d = t & 31;
            float s = 0.f;
            for (int c = 0; c < 16; c++) s += c2b[c * 6 + j] * u2[c * 192 + j * 32 + d];
            float sq = s * s;
            for (int off = 16; off; off >>= 1) sq += __shfl_xor(sq, off, 32);
            vv[t] = (sq / (1.f + sq)) * s / sqrtf(sq + EPSF);
        }
        __syncthreads();
        if (it < 2) {
            if (t < 96) {
                int c = t / 6, j = t - c * 6;
                float a = 0.f;
                for (int d = 0; d < 32; d++) a += u2[c * 192 + j * 32 + d] * vv[j * 32 + d];
                b2[t] += a;
            }
            __syncthreads();
        }
    }
    // outputs
    if (t < 192) out[(size_t)b * 192 + t] = vv[t];
    if (t < 6) {
        float s = 0.f;
        for (int d = 0; d < 32; d++) { float v = vv[t * 32 + d]; s += v * v; }
        magl[t] = sqrtf(s);
    }
    __syncthreads();
    int lab = label[b];
    if (t == 0) {
        float L = 0.f;
        int p = 0;
        float best = magl[0];
        for (int j = 0; j < 6; j++) {
            float mg = magl[j];
            if (mg > best) { best = mg; p = j; }
            float ml = fmaxf(0.9f - mg, 0.f); ml *= ml;
            float mr = fmaxf(mg - 0.1f, 0.f); mr *= mr;
            L += (j == lab) ? ml : 0.5f * mr;
        }
        marg[b] = L;
        out[6147 + b] = (float)p;
    }
    if (t < 32) cm[t] = vv[lab * 32 + t];
    __syncthreads();
    if (t < 128) {
        float a = rb1[t];
        for (int d = 0; d < 32; d++) a += cm[d] * rw1[d * 128 + t];
        hidl[t] = fmaxf(a, 0.f);
    }
    __syncthreads();
    bool act = t < 208;
    float rv = 0.f, rin = 0.f;
    if (act) {
        float a = rb2[t];
        for (int k = 0; k < 128; k++) a += hidl[k] * rw2[k * 208 + t];
        rv = 1.f / (1.f + expf(-a));
        rin = recon_in[(size_t)b * 208 + t];
    }
    red[t] = act ? rin : -INFINITY;
    __syncthreads();
    for (int s2 = 128; s2; s2 >>= 1) {
        if (t < s2) red[t] = fmaxf(red[t], red[t + s2]);
        __syncthreads();
    }
    float rmax = red[0];
    __syncthreads();
    float dpos = 0.f, dneg = 0.f;
    if (act) {
        float rec_val = rin / (rmax + EPSF);
        float d2 = rv - rec_val; d2 *= d2;
        bool neg = rin < 1e-5f;
        dpos = neg ? 0.f : d2;
        dneg = neg ? d2 : 0.f;
    }
    red[t] = dpos;
    __syncthreads();
    for (int s2 = 128; s2; s2 >>= 1) {
        if (t < s2) red[t] = fmaxf(red[t], red[t + s2]);
        __syncthreads();
    }
    float mp = red[0];
    __syncthreads();
    red[t] = dneg;
    __syncthreads();
    for (int s2 = 128; s2; s2 >>= 1) {
        if (t < s2) red[t] = fmaxf(red[t], red[t + s2]);
        __syncthreads();
    }
    if (t == 0) reconl[b] = mp + red[0];
}

__global__ void k_final(const float* __restrict__ marg, const float* __restrict__ reconl,
                        float* __restrict__ out) {
    int t = threadIdx.x;  // 64
    float m = (t < 32) ? marg[t] : 0.f;
    float r = (t < 32) ? reconl[t] : 0.f;
    for (int off = 16; off; off >>= 1) { m += __shfl_xor(m, off, 32); r += __shfl_xor(r, off, 32); }
    if (t == 0) {
        m /= 32.f;
        r /= 32.f;
        out[6144] = m + 0.1f * r;
        out[6145] = m;
        out[6146] = r;
    }
}

extern "C" void kernel_launch(void* const* d_in, const int* in_sizes, int n_in,
                              void* d_out, int out_size, void* d_ws, size_t ws_size,
                              hipStream_t stream) {
    const float* adj   = (const float*)d_in[0];
    const int*   n0    = (const int*)d_in[1];
    const int*   n1    = (const int*)d_in[2];
    const int*   n2    = (const int*)d_in[3];
    const int*   label = (const int*)d_in[4];
    const float* recon = (const float*)d_in[5];
    const float* e0    = (const float*)d_in[6];
    const float* e1    = (const float*)d_in[7];
    const float* e2    = (const float*)d_in[8];
    const float* gw0   = (const float*)d_in[9];
    const float* gb0   = (const float*)d_in[10];
    const float* gw1   = (const float*)d_in[11];
    const float* gb1   = (const float*)d_in[12];
    const float* gw2   = (const float*)d_in[13];
    const float* gb2   = (const float*)d_in[14];
    const float* aw1   = (const float*)d_in[15];
    const float* ab1   = (const float*)d_in[16];
    const float* aw2   = (const float*)d_in[17];
    const float* ab2   = (const float*)d_in[18];
    const float* Wg    = (const float*)d_in[19];
    const float* Wc    = (const float*)d_in[20];
    const float* rw1   = (const float*)d_in[21];
    const float* rb1   = (const float*)d_in[22];
    const float* rw2   = (const float*)d_in[23];
    const float* rb2   = (const float*)d_in[24];
    float* out = (float*)d_out;

    float* w = (float*)d_ws;
    float* dinv  = w; w += NB * NN;
    float* maskp = w; w += NB * NN;
    float* numn  = w; w += NB;
    float* feats = w; w += (size_t)NB * NN * GIN;
    float* Ybuf  = w; w += (size_t)NB * NN * 128;
    float* H     = w; w += (size_t)NB * NN * ATT;
    float* logit = w; w += NB * NN;
    float* bij   = w; w += (size_t)NB * NN * 96;
    float* cij   = w; w += (size_t)NB * NN * 96;
    float* Gs    = w; w += (size_t)NB * 6 * 4 * 1024;
    float* vg    = w; w += NB * 512;
    float* Wv    = w; w += NB * 6144;
    float* marg  = w; w += NB;
    float* recl  = w; w += NB;

    k_rowstats<<<NB * NN, 64, 0, stream>>>(adj, dinv, maskp);
    k_numnodes<<<NB, 64, 0, stream>>>(maskp, numn);
    k_gather<<<(NB * NN * GIN + 255) / 256, 256, 0, stream>>>(n0, n1, n2, e0, e1, e2, feats);

    k_gemm_dinv<192><<<NB * NN / 16, 256, 0, stream>>>(feats, 192, 0, gw0, gb0, dinv, Ybuf);
    k_adjmm<<<NB * 16, 256, 0, stream>>>(adj, Ybuf, dinv, H, 0);
    k_gemm_dinv<128><<<NB * NN / 16, 256, 0, stream>>>(H, ATT, 0, gw1, gb1, dinv, Ybuf);
    k_adjmm<<<NB * 16, 256, 0, stream>>>(adj, Ybuf, dinv, H, 128);
    k_gemm_dinv<128><<<NB * NN / 16, 256, 0, stream>>>(H, ATT, 128, gw2, gb2, dinv, Ybuf);
    k_adjmm<<<NB * 16, 256, 0, stream>>>(adj, Ybuf, dinv, H, 256);

    k_attn<<<NB * NN / 16, 384, 0, stream>>>(H, aw1, ab1, aw2, ab2, logit);
    k_attnsm<<<NB, 512, 0, stream>>>(logit, maskp);
    k_scaleH<<<NB * NN * ATT / 256, 256, 0, stream>>>(H, logit, numn);

    hipMemsetAsync(bij, 0, (size_t)NB * NN * 96 * sizeof(float), stream);
    for (int it = 0; it < 3; it++) {
        k_sm16<<<NB * NN * 96 / 256, 256, 0, stream>>>(bij, cij);
        k_Gs<<<NB * 24, 256, 0, stream>>>(cij, H, Gs);
        k_SV<<<NB, 512, 0, stream>>>(Gs, Wg, numn, vg);
        if (it < 2) {
            k_Wv<<<NB, 256, 0, stream>>>(vg, Wg, Wv);
            k_bup<<<NB * 16, 256, 0, stream>>>(H, Wv, bij);
        }
    }

    k_caps2<<<NB, 256, 0, stream>>>(vg, Wc, label, recon, rw1, rb1, rw2, rb2, out, marg, recl);
    k_final<<<1, 64, 0, stream>>>(marg, recl, out);
}

// Round 3
// 722.654 us; speedup vs baseline: 1.2436x; 1.2436x over previous
//
#include <hip/hip_runtime.h>
#include <hip/hip_bf16.h>
#include <math.h>

#define NB 32
#define NN 512
#define GIN 192
#define HID 128
#define ATT 384
#define EPSF 1e-11f

// ---------------- row stats: deg -> dinv, mask ----------------
__global__ void k_rowstats(const float* __restrict__ adj, float* __restrict__ dinv,
                           float* __restrict__ mask) {
    int row = blockIdx.x;                 // b*n
    const float* a = adj + (size_t)row * NN;
    int t = threadIdx.x;                  // 64
    float s = 0.f, m = 0.f;
    for (int i = t; i < NN; i += 64) { float v = a[i]; s += v; m = fmaxf(m, v); }
    for (int off = 32; off; off >>= 1) {
        s += __shfl_xor(s, off);
        m = fmaxf(m, __shfl_xor(m, off));
    }
    if (t == 0) {
        dinv[row] = s > 0.f ? 1.0f / sqrtf(s) : 0.f;
        mask[row] = m;
    }
}

__global__ void k_numnodes(const float* __restrict__ mask, float* __restrict__ numn) {
    int b = blockIdx.x, t = threadIdx.x;  // 64
    float s = 0.f;
    for (int i = t; i < NN; i += 64) s += mask[b * NN + i];
    for (int off = 32; off; off >>= 1) s += __shfl_xor(s, off);
    if (t == 0) numn[b] = s;
}

// ---------------- embedding gather ----------------
__global__ void k_gather(const int* __restrict__ n0, const int* __restrict__ n1,
                         const int* __restrict__ n2, const float* __restrict__ e0,
                         const float* __restrict__ e1, const float* __restrict__ e2,
                         float* __restrict__ feats) {
    int tid = blockIdx.x * 256 + threadIdx.x;
    if (tid >= NB * NN * GIN) return;
    int bn = tid / GIN, f = tid - bn * GIN;
    float v;
    if (f < 64)       v = e0[n0[bn] * 64 + f];
    else if (f < 128) v = e1[n1[bn] * 64 + (f - 64)];
    else              v = e2[n2[bn] * 64 + (f - 128)];
    feats[tid] = v;
}

// ================= shared 32x128 register-tiled GEMM inner loop =================
// xl: [32 rows][36 k-stride], wl: [32 k][128 cols]. Thread (rg=t>>5, cg=t&31)
// owns rows 4rg..4rg+3, cols 4cg..4cg+3. Per 4-k group: 8 ds_read_b128 + 64 FMA.
__device__ __forceinline__ void tile_mm(const float* __restrict__ xl,
                                        const float* __restrict__ wl,
                                        int rg, int cg, float acc[4][4]) {
#pragma unroll
    for (int mm0 = 0; mm0 < 32; mm0 += 4) {
        float a0[4], a1[4], a2[4], a3[4];
        *(float4*)a0 = *(const float4*)&xl[(4 * rg + 0) * 36 + mm0];
        *(float4*)a1 = *(const float4*)&xl[(4 * rg + 1) * 36 + mm0];
        *(float4*)a2 = *(const float4*)&xl[(4 * rg + 2) * 36 + mm0];
        *(float4*)a3 = *(const float4*)&xl[(4 * rg + 3) * 36 + mm0];
#pragma unroll
        for (int q = 0; q < 4; q++) {
            float b[4];
            *(float4*)b = *(const float4*)&wl[(mm0 + q) * 128 + 4 * cg];
#pragma unroll
            for (int c = 0; c < 4; c++) {
                acc[0][c] += a0[q] * b[c];
                acc[1][c] += a1[q] * b[c];
                acc[2][c] += a2[q] * b[c];
                acc[3][c] += a3[q] * b[c];
            }
        }
    }
}

// ---------------- dense GEMM: Y[r,:] = (X[r,:]@W + bias) * dinv[r] ----------------
template <int K>
__global__ __launch_bounds__(256) void k_gemmT(
    const float* __restrict__ X, int ldx, int xoff,
    const float* __restrict__ W, const float* __restrict__ bias,
    const float* __restrict__ dinv, float* __restrict__ Y) {
    __shared__ float xl[32 * 36];
    __shared__ float wl[32 * 128];
    int r0 = blockIdx.x * 32;
    int t = threadIdx.x;
    int rg = t >> 5, cg = t & 31;
    float acc[4][4] = {};
    for (int k0 = 0; k0 < K; k0 += 32) {
        for (int idx = t; idx < 1024; idx += 256) {
            int rr = idx >> 5, kk = idx & 31;
            xl[rr * 36 + kk] = X[(size_t)(r0 + rr) * ldx + xoff + k0 + kk];
        }
        for (int idx = t; idx < 4096; idx += 256) {
            int kk = idx >> 7, cc = idx & 127;
            wl[idx] = W[(size_t)(k0 + kk) * 128 + cc];
        }
        __syncthreads();
        tile_mm(xl, wl, rg, cg, acc);
        __syncthreads();
    }
    float bv[4];
    *(float4*)bv = *(const float4*)&bias[4 * cg];
#pragma unroll
    for (int r = 0; r < 4; r++) {
        int row = r0 + 4 * rg + r;
        float dv = dinv[row];
        float4 o;
        o.x = (acc[r][0] + bv[0]) * dv;
        o.y = (acc[r][1] + bv[1]) * dv;
        o.z = (acc[r][2] + bv[2]) * dv;
        o.w = (acc[r][3] + bv[3]) * dv;
        *(float4*)&Y[(size_t)row * 128 + 4 * cg] = o;
    }
}

// ---------------- adj GEMM: H[b,i,hoff:+128] = tanh(dinv_i * adj[b] @ Y[b]) ----------------
__global__ __launch_bounds__(256) void k_adjmm2(const float* __restrict__ adj,
                                                const float* __restrict__ Y,
                                                const float* __restrict__ dinv,
                                                float* __restrict__ H, int hoff) {
    __shared__ float xl[32 * 36];
    __shared__ float wl[32 * 128];
    int bb = blockIdx.x >> 4;
    int i0 = (blockIdx.x & 15) * 32;
    int t = threadIdx.x;
    int rg = t >> 5, cg = t & 31;
    float acc[4][4] = {};
    for (int m0 = 0; m0 < NN; m0 += 32) {
        for (int idx = t; idx < 1024; idx += 256) {
            int rr = idx >> 5, kk = idx & 31;
            xl[rr * 36 + kk] = adj[((size_t)bb * NN + i0 + rr) * NN + m0 + kk];
        }
        for (int idx = t; idx < 4096; idx += 256) {
            int kk = idx >> 7, cc = idx & 127;
            wl[idx] = Y[((size_t)bb * NN + m0 + kk) * 128 + cc];
        }
        __syncthreads();
        tile_mm(xl, wl, rg, cg, acc);
        __syncthreads();
    }
#pragma unroll
    for (int r = 0; r < 4; r++) {
        int grow = bb * NN + i0 + 4 * rg + r;
        float dv = dinv[grow];
        float4 o;
        o.x = tanhf(acc[r][0] * dv);
        o.y = tanhf(acc[r][1] * dv);
        o.z = tanhf(acc[r][2] * dv);
        o.w = tanhf(acc[r][3] * dv);
        *(float4*)&H[(size_t)grow * ATT + hoff + 4 * cg] = o;
    }
}

// ---------------- attention GEMM: P = tanh(H @ aw1 + ab1) ----------------
__global__ __launch_bounds__(256) void k_attn1(const float* __restrict__ H,
                                               const float* __restrict__ aw1,
                                               const float* __restrict__ ab1,
                                               float* __restrict__ P) {
    __shared__ float xl[32 * 36];
    __shared__ float wl[32 * 128];
    int r0 = blockIdx.x * 32;
    int c0 = blockIdx.y * 128;
    int t = threadIdx.x;
    int rg = t >> 5, cg = t & 31;
    float acc[4][4] = {};
    for (int k0 = 0; k0 < ATT; k0 += 32) {
        for (int idx = t; idx < 1024; idx += 256) {
            int rr = idx >> 5, kk = idx & 31;
            xl[rr * 36 + kk] = H[(size_t)(r0 + rr) * ATT + k0 + kk];
        }
        for (int idx = t; idx < 4096; idx += 256) {
            int kk = idx >> 7, cc = idx & 127;
            wl[idx] = aw1[(size_t)(k0 + kk) * ATT + c0 + cc];
        }
        __syncthreads();
        tile_mm(xl, wl, rg, cg, acc);
        __syncthreads();
    }
    float bv[4];
    *(float4*)bv = *(const float4*)&ab1[c0 + 4 * cg];
#pragma unroll
    for (int r = 0; r < 4; r++) {
        int row = r0 + 4 * rg + r;
        float4 o;
        o.x = tanhf(acc[r][0] + bv[0]);
        o.y = tanhf(acc[r][1] + bv[1]);
        o.z = tanhf(acc[r][2] + bv[2]);
        o.w = tanhf(acc[r][3] + bv[3]);
        *(float4*)&P[(size_t)row * ATT + c0 + 4 * cg] = o;
    }
}

// ---------------- logit[r] = P[r,:]@aw2 + ab2 ----------------
__global__ __launch_bounds__(256) void k_attn2(const float* __restrict__ P,
                                               const float* __restrict__ aw2,
                                               const float* __restrict__ ab2,
                                               float* __restrict__ logit) {
    int r0 = blockIdx.x * 32;
    int t = threadIdx.x;
    int r = t >> 3, l = t & 7;
    float s = 0.f;
#pragma unroll
    for (int k = 0; k < 12; k++) {
        int c = k * 32 + l * 4;
        float4 p = *(const float4*)&P[(size_t)(r0 + r) * ATT + c];
        float4 w = *(const float4*)&aw2[c];
        s += p.x * w.x + p.y * w.y + p.z * w.z + p.w * w.w;
    }
    s += __shfl_xor(s, 1);
    s += __shfl_xor(s, 2);
    s += __shfl_xor(s, 4);
    if (l == 0) logit[r0 + r] = s + ab2[0];
}

// ---------------- attention softmax over n, per batch ----------------
__global__ __launch_bounds__(512) void k_attnsm(float* __restrict__ logit,
                                                const float* __restrict__ mask) {
    __shared__ float red[8];
    __shared__ float red2[8];
    int b = blockIdx.x, t = threadIdx.x;
    float x = mask[b * NN + t] > 0.f ? logit[b * NN + t] : -INFINITY;
    float m = x;
    for (int off = 32; off; off >>= 1) m = fmaxf(m, __shfl_xor(m, off));
    if ((t & 63) == 0) red[t >> 6] = m;
    __syncthreads();
    float gm = red[0];
    for (int i = 1; i < 8; i++) gm = fmaxf(gm, red[i]);
    float e = expf(x - gm);
    float s = e;
    for (int off = 32; off; off >>= 1) s += __shfl_xor(s, off);
    if ((t & 63) == 0) red2[t >> 6] = s;
    __syncthreads();
    float gs = 0.f;
    for (int i = 0; i < 8; i++) gs += red2[i];
    logit[b * NN + t] = e / gs;
}

// ---------------- H *= attn * num_nodes (in place) ----------------
__global__ void k_scaleH(float* __restrict__ H, const float* __restrict__ attn,
                         const float* __restrict__ numn) {
    int tid = blockIdx.x * 256 + threadIdx.x;  // exactly NB*NN*ATT
    int bn = tid / ATT;
    H[tid] *= attn[bn] * numn[bn >> 9];
}

// ---------------- routing softmax over J=16 ----------------
__global__ void k_sm16(const float* __restrict__ bij, float* __restrict__ cij) {
    int gt = blockIdx.x * 256 + threadIdx.x;
    float v = bij[gt];
    float m = v;
    for (int off = 8; off; off >>= 1) m = fmaxf(m, __shfl_xor(m, off, 16));
    float e = expf(v - m), s = e;
    for (int off = 8; off; off >>= 1) s += __shfl_xor(s, off, 16);
    cij[gt] = e / s;
}

// ---------------- Gs[b,c,seg,j,i] = sum_{n in seg} c[b,n,c,j]*Hs[b,n,c,i] ----------------
__global__ __launch_bounds__(256) void k_Gs(const float* __restrict__ cij,
                                            const float* __restrict__ Hs,
                                            float* __restrict__ Gs) {
    int blk = blockIdx.x;  // b*24 + c*4 + seg
    int seg = blk & 3, c = (blk >> 2) % 6, b = blk / 24;
    __shared__ float ct[16 * 16];
    __shared__ float ht[16 * 64];
    int t = threadIdx.x;
    int i = t & 63, j0 = t >> 6;
    float acc[4] = {0.f, 0.f, 0.f, 0.f};
    int n0 = seg * 128;
    for (int nc = 0; nc < 128; nc += 16) {
        {
            int nn = t >> 4, jj = t & 15;
            ct[t] = cij[(((size_t)b * NN + n0 + nc + nn) * 6 + c) * 16 + jj];
        }
        for (int idx = t; idx < 1024; idx += 256) {
            int nn = idx >> 6, ii = idx & 63;
            ht[idx] = Hs[((size_t)b * NN + n0 + nc + nn) * ATT + c * 64 + ii];
        }
        __syncthreads();
        for (int nn = 0; nn < 16; nn++) {
            float hv = ht[nn * 64 + i];
#pragma unroll
            for (int q = 0; q < 4; q++) acc[q] += ct[nn * 16 + j0 * 4 + q] * hv;
        }
        __syncthreads();
    }
#pragma unroll
    for (int q = 0; q < 4; q++) {
        int j = j0 * 4 + q;
        Gs[(((size_t)b * 6 + c) * 4 + seg) * 1024 + j * 64 + i] = acc[q];
    }
}

// ---------------- s,v: v_g[b,j,d] = squash( sum_{c,i} Gsum*Wg / scale ) ----------------
__global__ __launch_bounds__(512) void k_SV(const float* __restrict__ Gs,
                                            const float* __restrict__ Wg,
                                            const float* __restrict__ numn,
                                            float* __restrict__ vg) {
    __shared__ float gsum[6144];
    int b = blockIdx.x, t = threadIdx.x;
    for (int idx = t; idx < 6144; idx += 512) {
        int c = idx >> 10, r = idx & 1023;
        const float* g = Gs + ((size_t)b * 6 + c) * 4096 + r;
        gsum[idx] = g[0] + g[1024] + g[2048] + g[3072];
    }
    __syncthreads();
    int j = t >> 5, d = t & 31;
    float s = 0.f;
    for (int c = 0; c < 6; c++)
        for (int i2 = 0; i2 < 64; i2++)
            s += gsum[(c * 16 + j) * 64 + i2] * Wg[(((size_t)c * 64 + i2) * 16 + j) * 32 + d];
    s /= numn[b];
    float sq = s * s;
    for (int off = 16; off; off >>= 1) sq += __shfl_xor(sq, off, 32);
    float v = (sq / (1.f + sq)) * s / sqrtf(sq + EPSF);
    vg[(size_t)b * 512 + t] = v;
}

// ---------------- Wv[b,c,i,j] = sum_d Wg[c,i,j,d]*v[b,j,d] ----------------
__global__ __launch_bounds__(256) void k_Wv(const float* __restrict__ vg,
                                            const float* __restrict__ Wg,
                                            float* __restrict__ Wv) {
    __shared__ float vl[512];
    int b = blockIdx.x, t = threadIdx.x;
    vl[t] = vg[(size_t)b * 512 + t];
    vl[t + 256] = vg[(size_t)b * 512 + t + 256];
    __syncthreads();
    for (int idx = t; idx < 6144; idx += 256) {
        int c = idx >> 10, r = idx & 1023, i = r >> 4, j = r & 15;
        float a = 0.f;
        const float* w = Wg + (((size_t)c * 64 + i) * 16 + j) * 32;
        for (int d = 0; d < 32; d++) a += w[d] * vl[j * 32 + d];
        Wv[(size_t)b * 6144 + idx] = a;
    }
}

// ---------------- b_ij += sum_i Hs[b,n,c,i]*Wv[b,c,i,j] ----------------
__global__ __launch_bounds__(256) void k_bup(const float* __restrict__ Hs,
                                             const float* __restrict__ Wv,
                                             float* __restrict__ bij) {
    int blk = blockIdx.x;
    int b = blk >> 4;
    int n0 = (blk & 15) * 32;
    __shared__ float wl[6144];
    __shared__ float hl[32 * ATT];
    int t = threadIdx.x;
    for (int idx = t; idx < 6144; idx += 256) wl[idx] = Wv[(size_t)b * 6144 + idx];
    for (int idx = t; idx < 32 * ATT; idx += 256)
        hl[idx] = Hs[((size_t)b * NN + n0) * ATT + idx];
    __syncthreads();
    for (int idx = t; idx < 3072; idx += 256) {
        int nn = idx / 96, r = idx % 96, c = r >> 4, j = r & 15;
        float a = 0.f;
        const float* h = hl + nn * ATT + c * 64;
        const float* w = wl + c * 1024 + j;
#pragma unroll
        for (int i2 = 0; i2 < 64; i2++) a += h[i2] * w[i2 * 16];
        bij[(((size_t)b * NN + n0 + nn) * 6 + c) * 16 + j] += a;
    }
}

// ---------------- second routing + losses, one block per batch ----------------
__global__ __launch_bounds__(256) void k_caps2(
    const float* __restrict__ vg, const float* __restrict__ Wc,
    const int* __restrict__ label, const float* __restrict__ recon_in,
    const float* __restrict__ rw1, const float* __restrict__ rb1,
    const float* __restrict__ rw2, const float* __restrict__ rb2,
    float* __restrict__ out, float* __restrict__ marg, float* __restrict__ reconl) {
    int b = blockIdx.x, t = threadIdx.x;
    __shared__ float vl[512];
    __shared__ float u2[3072];
    __shared__ float b2[96], c2b[96];
    __shared__ float vv[192];
    __shared__ float magl[6];
    __shared__ float cm[32];
    __shared__ float hidl[128];
    __shared__ float red[256];
    vl[t] = vg[(size_t)b * 512 + t];
    vl[t + 256] = vg[(size_t)b * 512 + t + 256];
    if (t < 96) b2[t] = 0.f;
    __syncthreads();
    for (int idx = t; idx < 3072; idx += 256) {
        int c = idx / 192, r = idx - c * 192;  // r = j*32+d
        float a = 0.f;
        const float* w = Wc + (size_t)c * 6144 + r;
        for (int i2 = 0; i2 < 32; i2++) a += vl[c * 32 + i2] * w[i2 * 192];
        u2[idx] = a;
    }
    __syncthreads();
    for (int it = 0; it < 3; it++) {
        if (t < 16) {
            float mx = -INFINITY;
            for (int j = 0; j < 6; j++) mx = fmaxf(mx, b2[t * 6 + j]);
            float e[6], s = 0.f;
            for (int j = 0; j < 6; j++) { e[j] = expf(b2[t * 6 + j] - mx); s += e[j]; }
            for (int j = 0; j < 6; j++) c2b[t * 6 + j] = e[j] / s;
        }
        __syncthreads();
        if (t < 192) {
            int j = t >> 5, d = t & 31;
            float s = 0.f;
            for (int c = 0; c < 16; c++) s += c2b[c * 6 + j] * u2[c * 192 + j * 32 + d];
            float sq = s * s;
            for (int off = 16; off; off >>= 1) sq += __shfl_xor(sq, off, 32);
            vv[t] = (sq / (1.f + sq)) * s / sqrtf(sq + EPSF);
        }
        __syncthreads();
        if (it < 2) {
            if (t < 96) {
                int c = t / 6, j = t - c * 6;
                float a = 0.f;
                for (int d = 0; d < 32; d++) a += u2[c * 192 + j * 32 + d] * vv[j * 32 + d];
                b2[t] += a;
            }
            __syncthreads();
        }
    }
    // outputs
    if (t < 192) out[(size_t)b * 192 + t] = vv[t];
    if (t < 6) {
        float s = 0.f;
        for (int d = 0; d < 32; d++) { float v = vv[t * 32 + d]; s += v * v; }
        magl[t] = sqrtf(s);
    }
    __syncthreads();
    int lab = label[b];
    if (t == 0) {
        float L = 0.f;
        int p = 0;
        float best = magl[0];
        for (int j = 0; j < 6; j++) {
            float mg = magl[j];
            if (mg > best) { best = mg; p = j; }
            float ml = fmaxf(0.9f - mg, 0.f); ml *= ml;
            float mr = fmaxf(mg - 0.1f, 0.f); mr *= mr;
            L += (j == lab) ? ml : 0.5f * mr;
        }
        marg[b] = L;
        out[6147 + b] = (float)p;
    }
    if (t < 32) cm[t] = vv[lab * 32 + t];
    __syncthreads();
    if (t < 128) {
        float a = rb1[t];
        for (int d = 0; d < 32; d++) a += cm[d] * rw1[d * 128 + t];
        hidl[t] = fmaxf(a, 0.f);
    }
    __syncthreads();
    bool act = t < 208;
    float rv = 0.f, rin = 0.f;
    if (act) {
        float a = rb2[t];
        for (int k = 0; k < 128; k++) a += hidl[k] * rw2[k * 208 + t];
        rv = 1.f / (1.f + expf(-a));
        rin = recon_in[(size_t)b * 208 + t];
    }
    red[t] = act ? rin : -INFINITY;
    __syncthreads();
    for (int s2 = 128; s2; s2 >>= 1) {
        if (t < s2) red[t] = fmaxf(red[t], red[t + s2]);
        __syncthreads();
    }
    float rmax = red[0];
    __syncthreads();
    float dpos = 0.f, dneg = 0.f;
    if (act) {
        float rec_val = rin / (rmax + EPSF);
        float d2 = rv - rec_val; d2 *= d2;
        bool neg = rin < 1e-5f;
        dpos = neg ? 0.f : d2;
        dneg = neg ? d2 : 0.f;
    }
    red[t] = dpos;
    __syncthreads();
    for (int s2 = 128; s2; s2 >>= 1) {
        if (t < s2) red[t] = fmaxf(red[t], red[t + s2]);
        __syncthreads();
    }
    float mp = red[0];
    __syncthreads();
    red[t] = dneg;
    __syncthreads();
    for (int s2 = 128; s2; s2 >>= 1) {
        if (t < s2) red[t] = fmaxf(red[t], red[t + s2]);
        __syncthreads();
    }
    if (t == 0) reconl[b] = mp + red[0];
}

__global__ void k_final(const float* __restrict__ marg, const float* __restrict__ reconl,
                        float* __restrict__ out) {
    int t = threadIdx.x;  // 64
    float m = (t < 32) ? marg[t] : 0.f;
    float r = (t < 32) ? reconl[t] : 0.f;
    for (int off = 16; off; off >>= 1) { m += __shfl_xor(m, off, 32); r += __shfl_xor(r, off, 32); }
    if (t == 0) {
        m /= 32.f;
        r /= 32.f;
        out[6144] = m + 0.1f * r;
        out[6145] = m;
        out[6146] = r;
    }
}

extern "C" void kernel_launch(void* const* d_in, const int* in_sizes, int n_in,
                              void* d_out, int out_size, void* d_ws, size_t ws_size,
                              hipStream_t stream) {
    const float* adj   = (const float*)d_in[0];
    const int*   n0    = (const int*)d_in[1];
    const int*   n1    = (const int*)d_in[2];
    const int*   n2    = (const int*)d_in[3];
    const int*   label = (const int*)d_in[4];
    const float* recon = (const float*)d_in[5];
    const float* e0    = (const float*)d_in[6];
    const float* e1    = (const float*)d_in[7];
    const float* e2    = (const float*)d_in[8];
    const float* gw0   = (const float*)d_in[9];
    const float* gb0   = (const float*)d_in[10];
    const float* gw1   = (const float*)d_in[11];
    const float* gb1   = (const float*)d_in[12];
    const float* gw2   = (const float*)d_in[13];
    const float* gb2   = (const float*)d_in[14];
    const float* aw1   = (const float*)d_in[15];
    const float* ab1   = (const float*)d_in[16];
    const float* aw2   = (const float*)d_in[17];
    const float* ab2   = (const float*)d_in[18];
    const float* Wg    = (const float*)d_in[19];
    const float* Wc    = (const float*)d_in[20];
    const float* rw1   = (const float*)d_in[21];
    const float* rb1   = (const float*)d_in[22];
    const float* rw2   = (const float*)d_in[23];
    const float* rb2   = (const float*)d_in[24];
    float* out = (float*)d_out;

    float* w = (float*)d_ws;
    float* dinv  = w; w += NB * NN;
    float* maskp = w; w += NB * NN;
    float* numn  = w; w += NB;
    float* feats = w; w += (size_t)NB * NN * GIN;
    float* Ybuf  = w; w += (size_t)NB * NN * 128;
    float* H     = w; w += (size_t)NB * NN * ATT;
    float* logit = w; w += NB * NN;
    float* bij   = w; w += (size_t)NB * NN * 96;
    float* cij   = w; w += (size_t)NB * NN * 96;
    float* Gs    = w; w += (size_t)NB * 6 * 4 * 1024;
    float* vg    = w; w += NB * 512;
    float* Wv    = w; w += NB * 6144;
    float* marg  = w; w += NB;
    float* recl  = w; w += NB;
    float* P     = w; w += (size_t)NB * NN * ATT;

    k_rowstats<<<NB * NN, 64, 0, stream>>>(adj, dinv, maskp);
    k_numnodes<<<NB, 64, 0, stream>>>(maskp, numn);
    k_gather<<<(NB * NN * GIN + 255) / 256, 256, 0, stream>>>(n0, n1, n2, e0, e1, e2, feats);

    k_gemmT<192><<<NB * NN / 32, 256, 0, stream>>>(feats, 192, 0, gw0, gb0, dinv, Ybuf);
    k_adjmm2<<<NB * 16, 256, 0, stream>>>(adj, Ybuf, dinv, H, 0);
    k_gemmT<128><<<NB * NN / 32, 256, 0, stream>>>(H, ATT, 0, gw1, gb1, dinv, Ybuf);
    k_adjmm2<<<NB * 16, 256, 0, stream>>>(adj, Ybuf, dinv, H, 128);
    k_gemmT<128><<<NB * NN / 32, 256, 0, stream>>>(H, ATT, 128, gw2, gb2, dinv, Ybuf);
    k_adjmm2<<<NB * 16, 256, 0, stream>>>(adj, Ybuf, dinv, H, 256);

    k_attn1<<<dim3(NB * NN / 32, 3), 256, 0, stream>>>(H, aw1, ab1, P);
    k_attn2<<<NB * NN / 32, 256, 0, stream>>>(P, aw2, ab2, logit);
    k_attnsm<<<NB, 512, 0, stream>>>(logit, maskp);
    k_scaleH<<<NB * NN * ATT / 256, 256, 0, stream>>>(H, logit, numn);

    hipMemsetAsync(bij, 0, (size_t)NB * NN * 96 * sizeof(float), stream);
    for (int it = 0; it < 3; it++) {
        k_sm16<<<NB * NN * 96 / 256, 256, 0, stream>>>(bij, cij);
        k_Gs<<<NB * 24, 256, 0, stream>>>(cij, H, Gs);
        k_SV<<<NB, 512, 0, stream>>>(Gs, Wg, numn, vg);
        if (it < 2) {
            k_Wv<<<NB, 256, 0, stream>>>(vg, Wg, Wv);
            k_bup<<<NB * 16, 256, 0, stream>>>(H, Wv, bij);
        }
    }

    k_caps2<<<NB, 256, 0, stream>>>(vg, Wc, label, recon, rw1, rb1, rw2, rb2, out, marg, recl);
    k_final<<<1, 64, 0, stream>>>(marg, recl, out);
}

// Round 4
// 572.952 us; speedup vs baseline: 1.5685x; 1.2613x over previous
//
#include <hip/hip_runtime.h>
#include <hip/hip_bf16.h>
#include <math.h>

#define NB 32
#define NN 512
#define GIN 192
#define ATT 384
#define EPSF 1e-11f

typedef __attribute__((ext_vector_type(4))) float f32x4;
typedef __attribute__((ext_vector_type(8))) short short8;

__device__ __forceinline__ ushort bfhi(float f) {
    uint u = __float_as_uint(f);
    return (ushort)((u + 0x7FFFu + ((u >> 16) & 1u)) >> 16);
}
__device__ __forceinline__ float bff(ushort h) {
    return __uint_as_float(((uint)h) << 16);
}
__device__ __forceinline__ void bfsplit(float f, ushort& hi, ushort& lo) {
    hi = bfhi(f);
    lo = bfhi(f - bff(hi));
}

// ---------------- row stats: deg -> dinv, mask ----------------
__global__ void k_rowstats(const float* __restrict__ adj, float* __restrict__ dinv,
                           float* __restrict__ mask) {
    int row = blockIdx.x;
    const float* a = adj + (size_t)row * NN;
    int t = threadIdx.x;  // 64
    float s = 0.f, m = 0.f;
    for (int i = t; i < NN; i += 64) { float v = a[i]; s += v; m = fmaxf(m, v); }
    for (int off = 32; off; off >>= 1) {
        s += __shfl_xor(s, off);
        m = fmaxf(m, __shfl_xor(m, off));
    }
    if (t == 0) {
        dinv[row] = s > 0.f ? 1.0f / sqrtf(s) : 0.f;
        mask[row] = m;
    }
}

__global__ void k_numnodes(const float* __restrict__ mask, float* __restrict__ numn) {
    int b = blockIdx.x, t = threadIdx.x;  // 64
    float s = 0.f;
    for (int i = t; i < NN; i += 64) s += mask[b * NN + i];
    for (int off = 32; off; off >>= 1) s += __shfl_xor(s, off);
    if (t == 0) numn[b] = s;
}

// ---------------- adj fp32 -> bf16 (exact: adj is 0/1) ----------------
__global__ void k_cvtadj(const float* __restrict__ a, ushort* __restrict__ o, int n4) {
    int i = blockIdx.x * 256 + threadIdx.x;
    if (i >= n4) return;
    float4 v = ((const float4*)a)[i];
    ushort4 u;
    u.x = bfhi(v.x); u.y = bfhi(v.y); u.z = bfhi(v.z); u.w = bfhi(v.w);
    ((ushort4*)o)[i] = u;
}

// ---------------- embedding gather -> split bf16 planes ----------------
__global__ void k_gather(const int* __restrict__ n0, const int* __restrict__ n1,
                         const int* __restrict__ n2, const float* __restrict__ e0,
                         const float* __restrict__ e1, const float* __restrict__ e2,
                         ushort* __restrict__ fh, ushort* __restrict__ fl) {
    int tid = blockIdx.x * 256 + threadIdx.x;
    if (tid >= NB * NN * GIN) return;
    int bn = tid / GIN, f = tid - bn * GIN;
    float v;
    if (f < 64)       v = e0[n0[bn] * 64 + f];
    else if (f < 128) v = e1[n1[bn] * 64 + (f - 64)];
    else              v = e2[n2[bn] * 64 + (f - 128)];
    ushort h, lo;
    bfsplit(v, h, lo);
    fh[tid] = h; fl[tid] = lo;
}

// ---------------- W [K][N] fp32 -> Wt [N][K] split bf16 ----------------
__global__ __launch_bounds__(256) void k_twt(const float* __restrict__ W, int K, int N,
                                             ushort* __restrict__ Th, ushort* __restrict__ Tl) {
    __shared__ float tile[32][33];
    int k0 = blockIdx.x * 32, n0 = blockIdx.y * 32;
    int t = threadIdx.x, tx = t & 31, ty = t >> 5;  // ty 0..7
#pragma unroll
    for (int r = 0; r < 4; r++)
        tile[ty + r * 8][tx] = W[(size_t)(k0 + ty + r * 8) * N + n0 + tx];
    __syncthreads();
#pragma unroll
    for (int r = 0; r < 4; r++) {
        int nn = ty + r * 8;
        float v = tile[tx][nn];
        ushort h, lo;
        bfsplit(v, h, lo);
        size_t o = (size_t)(n0 + nn) * K + k0 + tx;
        Th[o] = h; Tl[o] = lo;
    }
}

// ================= MFMA split-bf16 GEMM =================
// A: [M][lda] bf16 planes (Ah + optional Al), K-contiguous. B: [N][KK] bf16 planes.
// Block tile 128x128, 4 waves 2x2, wave tile 64x64, K-step 32.
// EPI 0: Yt = (acc + bias[c]) * dinv[r], write transposed bf16 planes per batch
// EPI 1: Hb = tanh(acc * dinv[r]) -> bf16 planes at col hoff+c (B += batch*128*512)
// EPI 2: P = tanh(acc + bias[c]) -> fp32 row-major [*,ATT] at col n0+c
template <int KK, bool AEX, int EPI>
__global__ __launch_bounds__(256) void k_mfg(
    const ushort* __restrict__ Ah, const ushort* __restrict__ Al, int lda,
    const ushort* __restrict__ Bh, const ushort* __restrict__ Bl,
    const float* __restrict__ bias, const float* __restrict__ dinv,
    ushort* __restrict__ O1, ushort* __restrict__ O2, float* __restrict__ Of,
    int hoff) {
    __shared__ ushort Ash[4096], Asl[4096], Bsh[4096], Bsl[4096];
    int t = threadIdx.x;
    int m0 = blockIdx.x * 128;
    int n0 = blockIdx.y * 128;
    if (EPI == 1) {
        size_t off = (size_t)(m0 >> 9) * 128 * 512;
        Bh += off; Bl += off;
    }
    int l = t & 63, w = t >> 6, wr = w >> 1, wc = w & 1;
    f32x4 z = {0.f, 0.f, 0.f, 0.f};
    f32x4 acc[4][4];
#pragma unroll
    for (int i = 0; i < 4; i++)
#pragma unroll
        for (int j = 0; j < 4; j++) acc[i][j] = z;

    for (int k0 = 0; k0 < KK; k0 += 32) {
        if (k0) __syncthreads();
#pragma unroll
        for (int f = 0; f < 2; f++) {
            int fi = t + f * 256;
            int ll = fi & 63, g16 = fi >> 6;
            int rowA = m0 + g16 * 16 + (ll & 15);
            int rowB = n0 + g16 * 16 + (ll & 15);
            int ko = k0 + (ll >> 4) * 8;
            *(short8*)&Ash[fi * 8] = *(const short8*)&Ah[(size_t)rowA * lda + ko];
            if constexpr (!AEX)
                *(short8*)&Asl[fi * 8] = *(const short8*)&Al[(size_t)rowA * lda + ko];
            *(short8*)&Bsh[fi * 8] = *(const short8*)&Bh[(size_t)rowB * KK + ko];
            *(short8*)&Bsl[fi * 8] = *(const short8*)&Bl[(size_t)rowB * KK + ko];
        }
        __syncthreads();
        short8 ah[4], al[4], bh[4], bl[4];
#pragma unroll
        for (int i = 0; i < 4; i++) {
            ah[i] = *(const short8*)&Ash[((wr * 4 + i) * 64 + l) * 8];
            if constexpr (!AEX) al[i] = *(const short8*)&Asl[((wr * 4 + i) * 64 + l) * 8];
        }
#pragma unroll
        for (int j = 0; j < 4; j++) {
            bh[j] = *(const short8*)&Bsh[((wc * 4 + j) * 64 + l) * 8];
            bl[j] = *(const short8*)&Bsl[((wc * 4 + j) * 64 + l) * 8];
        }
#pragma unroll
        for (int i = 0; i < 4; i++)
#pragma unroll
            for (int j = 0; j < 4; j++) {
                acc[i][j] = __builtin_amdgcn_mfma_f32_16x16x32_bf16(ah[i], bh[j], acc[i][j], 0, 0, 0);
                acc[i][j] = __builtin_amdgcn_mfma_f32_16x16x32_bf16(ah[i], bl[j], acc[i][j], 0, 0, 0);
                if constexpr (!AEX)
                    acc[i][j] = __builtin_amdgcn_mfma_f32_16x16x32_bf16(al[i], bh[j], acc[i][j], 0, 0, 0);
            }
    }
    // epilogue
#pragma unroll
    for (int i = 0; i < 4; i++)
#pragma unroll
        for (int j = 0; j < 4; j++) {
            int gc = n0 + (wc * 4 + j) * 16 + (l & 15);
            int gr0 = m0 + (wr * 4 + i) * 16 + 4 * (l >> 4);
            if constexpr (EPI == 0) {
                float bv = bias[gc];
                size_t ob = (size_t)(m0 >> 9) * 65536 + (size_t)gc * 512 + (gr0 & 511);
#pragma unroll
                for (int r = 0; r < 4; r++) {
                    float v = (acc[i][j][r] + bv) * dinv[gr0 + r];
                    ushort h, lo;
                    bfsplit(v, h, lo);
                    O1[ob + r] = h; O2[ob + r] = lo;
                }
            } else if constexpr (EPI == 1) {
#pragma unroll
                for (int r = 0; r < 4; r++) {
                    float v = tanhf(acc[i][j][r] * dinv[gr0 + r]);
                    ushort h, lo;
                    bfsplit(v, h, lo);
                    size_t o = (size_t)(gr0 + r) * ATT + hoff + gc;
                    O1[o] = h; O2[o] = lo;
                }
            } else {
                float bv = bias[gc];
#pragma unroll
                for (int r = 0; r < 4; r++)
                    Of[(size_t)(gr0 + r) * ATT + gc] = tanhf(acc[i][j][r] + bv);
            }
        }
}

// ---------------- logit[r] = P[r,:]@aw2 + ab2 ----------------
__global__ __launch_bounds__(256) void k_attn2(const float* __restrict__ P,
                                               const float* __restrict__ aw2,
                                               const float* __restrict__ ab2,
                                               float* __restrict__ logit) {
    int r0 = blockIdx.x * 32;
    int t = threadIdx.x;
    int r = t >> 3, l = t & 7;
    float s = 0.f;
#pragma unroll
    for (int k = 0; k < 12; k++) {
        int c = k * 32 + l * 4;
        float4 p = *(const float4*)&P[(size_t)(r0 + r) * ATT + c];
        float4 w = *(const float4*)&aw2[c];
        s += p.x * w.x + p.y * w.y + p.z * w.z + p.w * w.w;
    }
    s += __shfl_xor(s, 1);
    s += __shfl_xor(s, 2);
    s += __shfl_xor(s, 4);
    if (l == 0) logit[r0 + r] = s + ab2[0];
}

// ---------------- attention softmax over n, per batch ----------------
__global__ __launch_bounds__(512) void k_attnsm(float* __restrict__ logit,
                                                const float* __restrict__ mask) {
    __shared__ float red[8];
    __shared__ float red2[8];
    int b = blockIdx.x, t = threadIdx.x;
    float x = mask[b * NN + t] > 0.f ? logit[b * NN + t] : -INFINITY;
    float m = x;
    for (int off = 32; off; off >>= 1) m = fmaxf(m, __shfl_xor(m, off));
    if ((t & 63) == 0) red[t >> 6] = m;
    __syncthreads();
    float gm = red[0];
    for (int i = 1; i < 8; i++) gm = fmaxf(gm, red[i]);
    float e = expf(x - gm);
    float s = e;
    for (int off = 32; off; off >>= 1) s += __shfl_xor(s, off);
    if ((t & 63) == 0) red2[t >> 6] = s;
    __syncthreads();
    float gs = 0.f;
    for (int i = 0; i < 8; i++) gs += red2[i];
    logit[b * NN + t] = e / gs;
}

// ---------------- H *= attn * num_nodes (both planes, in place) ----------------
__global__ void k_scaleHb(ushort* __restrict__ Hh, ushort* __restrict__ Hl,
                          const float* __restrict__ attn, const float* __restrict__ numn) {
    int tid = blockIdx.x * 256 + threadIdx.x;  // exactly NB*NN*ATT
    int bn = tid / ATT;
    float f = bff(Hh[tid]) + bff(Hl[tid]);
    f *= attn[bn] * numn[bn >> 9];
    ushort h, lo;
    bfsplit(f, h, lo);
    Hh[tid] = h; Hl[tid] = lo;
}

// ---------------- routing softmax over J=16 ----------------
__global__ void k_sm16(const float* __restrict__ bij, float* __restrict__ cij) {
    int gt = blockIdx.x * 256 + threadIdx.x;
    float v = bij[gt];
    float m = v;
    for (int off = 8; off; off >>= 1) m = fmaxf(m, __shfl_xor(m, off, 16));
    float e = expf(v - m), s = e;
    for (int off = 8; off; off >>= 1) s += __shfl_xor(s, off, 16);
    cij[gt] = e / s;
}

// ---------------- Gs[b,c,seg,j,i] = sum_{n in seg} c[b,n,c,j]*Hs[b,n,c,i] ----------------
__global__ __launch_bounds__(256) void k_Gs(const float* __restrict__ cij,
                                            const ushort* __restrict__ Hh,
                                            const ushort* __restrict__ Hl,
                                            float* __restrict__ Gs) {
    int blk = blockIdx.x;  // b*24 + c*4 + seg
    int seg = blk & 3, c = (blk >> 2) % 6, b = blk / 24;
    __shared__ float ct[16 * 16];
    __shared__ float ht[16 * 64];
    int t = threadIdx.x;
    int i = t & 63, j0 = t >> 6;
    float acc[4] = {0.f, 0.f, 0.f, 0.f};
    int n0 = seg * 128;
    for (int nc = 0; nc < 128; nc += 16) {
        {
            int nn = t >> 4, jj = t & 15;
            ct[t] = cij[(((size_t)b * NN + n0 + nc + nn) * 6 + c) * 16 + jj];
        }
        for (int idx = t; idx < 1024; idx += 256) {
            int nn = idx >> 6, ii = idx & 63;
            size_t o = ((size_t)b * NN + n0 + nc + nn) * ATT + c * 64 + ii;
            ht[idx] = bff(Hh[o]) + bff(Hl[o]);
        }
        __syncthreads();
        for (int nn = 0; nn < 16; nn++) {
            float hv = ht[nn * 64 + i];
#pragma unroll
            for (int q = 0; q < 4; q++) acc[q] += ct[nn * 16 + j0 * 4 + q] * hv;
        }
        __syncthreads();
    }
#pragma unroll
    for (int q = 0; q < 4; q++) {
        int j = j0 * 4 + q;
        Gs[(((size_t)b * 6 + c) * 4 + seg) * 1024 + j * 64 + i] = acc[q];
    }
}

// ---------------- s,v: v_g[b,j,d] = squash( sum_{c,i} Gsum*Wg / scale ) ----------------
__global__ __launch_bounds__(512) void k_SV(const float* __restrict__ Gs,
                                            const float* __restrict__ Wg,
                                            const float* __restrict__ numn,
                                            float* __restrict__ vg) {
    __shared__ float gsum[6144];
    int b = blockIdx.x, t = threadIdx.x;
    for (int idx = t; idx < 6144; idx += 512) {
        int c = idx >> 10, r = idx & 1023;
        const float* g = Gs + ((size_t)b * 6 + c) * 4096 + r;
        gsum[idx] = g[0] + g[1024] + g[2048] + g[3072];
    }
    __syncthreads();
    int j = t >> 5, d = t & 31;
    float s = 0.f;
    for (int c = 0; c < 6; c++)
        for (int i2 = 0; i2 < 64; i2++)
            s += gsum[(c * 16 + j) * 64 + i2] * Wg[(((size_t)c * 64 + i2) * 16 + j) * 32 + d];
    s /= numn[b];
    float sq = s * s;
    for (int off = 16; off; off >>= 1) sq += __shfl_xor(sq, off, 32);
    float v = (sq / (1.f + sq)) * s / sqrtf(sq + EPSF);
    vg[(size_t)b * 512 + t] = v;
}

// ---------------- Wv[b,c,i,j] = sum_d Wg[c,i,j,d]*v[b,j,d] ----------------
__global__ __launch_bounds__(256) void k_Wv(const float* __restrict__ vg,
                                            const float* __restrict__ Wg,
                                            float* __restrict__ Wv) {
    __shared__ float vl[512];
    int b = blockIdx.x, t = threadIdx.x;
    vl[t] = vg[(size_t)b * 512 + t];
    vl[t + 256] = vg[(size_t)b * 512 + t + 256];
    __syncthreads();
    for (int idx = t; idx < 6144; idx += 256) {
        int c = idx >> 10, r = idx & 1023, i = r >> 4, j = r & 15;
        float a = 0.f;
        const float* w = Wg + (((size_t)c * 64 + i) * 16 + j) * 32;
        for (int d = 0; d < 32; d++) a += w[d] * vl[j * 32 + d];
        Wv[(size_t)b * 6144 + idx] = a;
    }
}

// ---------------- b_ij += sum_i Hs[b,n,c,i]*Wv[b,c,i,j] ----------------
__global__ __launch_bounds__(256) void k_bup(const ushort* __restrict__ Hh,
                                             const ushort* __restrict__ Hl,
                                             const float* __restrict__ Wv,
                                             float* __restrict__ bij) {
    int blk = blockIdx.x;
    int b = blk >> 4;
    int n0 = (blk & 15) * 32;
    __shared__ float wl[6144];
    __shared__ float hl[32 * ATT];
    int t = threadIdx.x;
    for (int idx = t; idx < 6144; idx += 256) wl[idx] = Wv[(size_t)b * 6144 + idx];
    for (int idx = t; idx < 32 * ATT; idx += 256) {
        size_t o = ((size_t)b * NN + n0) * ATT + idx;
        hl[idx] = bff(Hh[o]) + bff(Hl[o]);
    }
    __syncthreads();
    for (int idx = t; idx < 3072; idx += 256) {
        int nn = idx / 96, r = idx % 96, c = r >> 4, j = r & 15;
        float a = 0.f;
        const float* h = hl + nn * ATT + c * 64;
        const float* w = wl + c * 1024 + j;
#pragma unroll
        for (int i2 = 0; i2 < 64; i2++) a += h[i2] * w[i2 * 16];
        bij[(((size_t)b * NN + n0 + nn) * 6 + c) * 16 + j] += a;
    }
}

// ---------------- second routing + losses, one block per batch ----------------
__global__ __launch_bounds__(256) void k_caps2(
    const float* __restrict__ vg, const float* __restrict__ Wc,
    const int* __restrict__ label, const float* __restrict__ recon_in,
    const float* __restrict__ rw1, const float* __restrict__ rb1,
    const float* __restrict__ rw2, const float* __restrict__ rb2,
    float* __restrict__ out, float* __restrict__ marg, float* __restrict__ reconl) {
    int b = blockIdx.x, t = threadIdx.x;
    __shared__ float vl[512];
    __shared__ float u2[3072];
    __shared__ float b2[96], c2b[96];
    __shared__ float vv[192];
    __shared__ float magl[6];
    __shared__ float cm[32];
    __shared__ float hidl[128];
    __shared__ float red[256];
    vl[t] = vg[(size_t)b * 512 + t];
    vl[t + 256] = vg[(size_t)b * 512 + t + 256];
    if (t < 96) b2[t] = 0.f;
    __syncthreads();
    for (int idx = t; idx < 3072; idx += 256) {
        int c = idx / 192, r = idx - c * 192;  // r = j*32+d
        float a = 0.f;
        const float* w = Wc + (size_t)c * 6144 + r;
        for (int i2 = 0; i2 < 32; i2++) a += vl[c * 32 + i2] * w[i2 * 192];
        u2[idx] = a;
    }
    __syncthreads();
    for (int it = 0; it < 3; it++) {
        if (t < 16) {
            float mx = -INFINITY;
            for (int j = 0; j < 6; j++) mx = fmaxf(mx, b2[t * 6 + j]);
            float e[6], s = 0.f;
            for (int j = 0; j < 6; j++) { e[j] = expf(b2[t * 6 + j] - mx); s += e[j]; }
            for (int j = 0; j < 6; j++) c2b[t * 6 + j] = e[j] / s;
        }
        __syncthreads();
        if (t < 192) {
            int j = t >> 5, d = t & 31;
            float s = 0.f;
            for (int c = 0; c < 16; c++) s += c2b[c * 6 + j] * u2[c * 192 + j * 32 + d];
            float sq = s * s;
            for (int off = 16; off; off >>= 1) sq += __shfl_xor(sq, off, 32);
            vv[t] = (sq / (1.f + sq)) * s / sqrtf(sq + EPSF);
        }
        __syncthreads();
        if (it < 2) {
            if (t < 96) {
                int c = t / 6, j = t - c * 6;
                float a = 0.f;
                for (int d = 0; d < 32; d++) a += u2[c * 192 + j * 32 + d] * vv[j * 32 + d];
                b2[t] += a;
            }
            __syncthreads();
        }
    }
    if (t < 192) out[(size_t)b * 192 + t] = vv[t];
    if (t < 6) {
        float s = 0.f;
        for (int d = 0; d < 32; d++) { float v = vv[t * 32 + d]; s += v * v; }
        magl[t] = sqrtf(s);
    }
    __syncthreads();
    int lab = label[b];
    if (t == 0) {
        float L = 0.f;
        int p = 0;
        float best = magl[0];
        for (int j = 0; j < 6; j++) {
            float mg = magl[j];
            if (mg > best) { best = mg; p = j; }
            float ml = fmaxf(0.9f - mg, 0.f); ml *= ml;
            float mr = fmaxf(mg - 0.1f, 0.f); mr *= mr;
            L += (j == lab) ? ml : 0.5f * mr;
        }
        marg[b] = L;
        out[6147 + b] = (float)p;
    }
    if (t < 32) cm[t] = vv[lab * 32 + t];
    __syncthreads();
    if (t < 128) {
        float a = rb1[t];
        for (int d = 0; d < 32; d++) a += cm[d] * rw1[d * 128 + t];
        hidl[t] = fmaxf(a, 0.f);
    }
    __syncthreads();
    bool act = t < 208;
    float rv = 0.f, rin = 0.f;
    if (act) {
        float a = rb2[t];
        for (int k = 0; k < 128; k++) a += hidl[k] * rw2[k * 208 + t];
        rv = 1.f / (1.f + expf(-a));
        rin = recon_in[(size_t)b * 208 + t];
    }
    red[t] = act ? rin : -INFINITY;
    __syncthreads();
    for (int s2 = 128; s2; s2 >>= 1) {
        if (t < s2) red[t] = fmaxf(red[t], red[t + s2]);
        __syncthreads();
    }
    float rmax = red[0];
    __syncthreads();
    float dpos = 0.f, dneg = 0.f;
    if (act) {
        float rec_val = rin / (rmax + EPSF);
        float d2 = rv - rec_val; d2 *= d2;
        bool neg = rin < 1e-5f;
        dpos = neg ? 0.f : d2;
        dneg = neg ? d2 : 0.f;
    }
    red[t] = dpos;
    __syncthreads();
    for (int s2 = 128; s2; s2 >>= 1) {
        if (t < s2) red[t] = fmaxf(red[t], red[t + s2]);
        __syncthreads();
    }
    float mp = red[0];
    __syncthreads();
    red[t] = dneg;
    __syncthreads();
    for (int s2 = 128; s2; s2 >>= 1) {
        if (t < s2) red[t] = fmaxf(red[t], red[t + s2]);
        __syncthreads();
    }
    if (t == 0) reconl[b] = mp + red[0];
}

__global__ void k_final(const float* __restrict__ marg, const float* __restrict__ reconl,
                        float* __restrict__ out) {
    int t = threadIdx.x;  // 64
    float m = (t < 32) ? marg[t] : 0.f;
    float r = (t < 32) ? reconl[t] : 0.f;
    for (int off = 16; off; off >>= 1) { m += __shfl_xor(m, off, 32); r += __shfl_xor(r, off, 32); }
    if (t == 0) {
        m /= 32.f;
        r /= 32.f;
        out[6144] = m + 0.1f * r;
        out[6145] = m;
        out[6146] = r;
    }
}

extern "C" void kernel_launch(void* const* d_in, const int* in_sizes, int n_in,
                              void* d_out, int out_size, void* d_ws, size_t ws_size,
                              hipStream_t stream) {
    const float* adj   = (const float*)d_in[0];
    const int*   n0    = (const int*)d_in[1];
    const int*   n1    = (const int*)d_in[2];
    const int*   n2    = (const int*)d_in[3];
    const int*   label = (const int*)d_in[4];
    const float* recon = (const float*)d_in[5];
    const float* e0    = (const float*)d_in[6];
    const float* e1    = (const float*)d_in[7];
    const float* e2    = (const float*)d_in[8];
    const float* gw0   = (const float*)d_in[9];
    const float* gb0   = (const float*)d_in[10];
    const float* gw1   = (const float*)d_in[11];
    const float* gb1   = (const float*)d_in[12];
    const float* gw2   = (const float*)d_in[13];
    const float* gb2   = (const float*)d_in[14];
    const float* aw1   = (const float*)d_in[15];
    const float* ab1   = (const float*)d_in[16];
    const float* aw2   = (const float*)d_in[17];
    const float* ab2   = (const float*)d_in[18];
    const float* Wg    = (const float*)d_in[19];
    const float* Wc    = (const float*)d_in[20];
    const float* rw1   = (const float*)d_in[21];
    const float* rb1   = (const float*)d_in[22];
    const float* rw2   = (const float*)d_in[23];
    const float* rb2   = (const float*)d_in[24];
    float* out = (float*)d_out;

    char* p = (char*)d_ws;
    auto alloc = [&](size_t bytes) { char* r = p; p += (bytes + 255) & ~(size_t)255; return r; };
    float*  dinv   = (float*)alloc(NB * NN * 4);
    float*  maskp  = (float*)alloc(NB * NN * 4);
    float*  numn   = (float*)alloc(NB * 4);
    float*  logit  = (float*)alloc(NB * NN * 4);
    float*  bij    = (float*)alloc((size_t)NB * NN * 96 * 4);
    float*  cij    = (float*)alloc((size_t)NB * NN * 96 * 4);
    float*  Gs     = (float*)alloc((size_t)NB * 24576 * 4);
    float*  vg     = (float*)alloc(NB * 512 * 4);
    float*  Wv     = (float*)alloc(NB * 6144 * 4);
    float*  marg   = (float*)alloc(NB * 4);
    float*  recl   = (float*)alloc(NB * 4);
    ushort* gwt0h  = (ushort*)alloc(128 * 192 * 2);
    ushort* gwt0l  = (ushort*)alloc(128 * 192 * 2);
    ushort* gwt1h  = (ushort*)alloc(128 * 128 * 2);
    ushort* gwt1l  = (ushort*)alloc(128 * 128 * 2);
    ushort* gwt2h  = (ushort*)alloc(128 * 128 * 2);
    ushort* gwt2l  = (ushort*)alloc(128 * 128 * 2);
    ushort* aw1th  = (ushort*)alloc(384 * 384 * 2);
    ushort* aw1tl  = (ushort*)alloc(384 * 384 * 2);
    ushort* Yth    = (ushort*)alloc((size_t)NB * 128 * 512 * 2);
    ushort* Ytl    = (ushort*)alloc((size_t)NB * 128 * 512 * 2);
    ushort* Hbh    = (ushort*)alloc((size_t)NB * NN * ATT * 2);
    ushort* Hbl    = (ushort*)alloc((size_t)NB * NN * ATT * 2);
    // overlay region: featsb planes + adjb, later reused for P
    char*   ov     = alloc((size_t)NB * NN * GIN * 2 * 2 + (size_t)NB * NN * NN * 2);
    ushort* fbh    = (ushort*)ov;
    ushort* fbl    = fbh + (size_t)NB * NN * GIN;
    ushort* adjb   = fbl + (size_t)NB * NN * GIN;
    float*  P      = (float*)ov;  // 25.2MB <= 29.4MB, used only after adjb dead

    k_rowstats<<<NB * NN, 64, 0, stream>>>(adj, dinv, maskp);
    k_numnodes<<<NB, 64, 0, stream>>>(maskp, numn);
    k_cvtadj<<<(NB * NN * NN / 4 + 255) / 256, 256, 0, stream>>>(adj, adjb, NB * NN * NN / 4);
    k_gather<<<(NB * NN * GIN + 255) / 256, 256, 0, stream>>>(n0, n1, n2, e0, e1, e2, fbh, fbl);
    k_twt<<<dim3(6, 4), 256, 0, stream>>>(gw0, 192, 128, gwt0h, gwt0l);
    k_twt<<<dim3(4, 4), 256, 0, stream>>>(gw1, 128, 128, gwt1h, gwt1l);
    k_twt<<<dim3(4, 4), 256, 0, stream>>>(gw2, 128, 128, gwt2h, gwt2l);
    k_twt<<<dim3(12, 12), 256, 0, stream>>>(aw1, 384, 384, aw1th, aw1tl);

    k_mfg<192, false, 0><<<128, 256, 0, stream>>>(fbh, fbl, 192, gwt0h, gwt0l, gb0, dinv,
                                                  Yth, Ytl, nullptr, 0);
    k_mfg<512, true, 1><<<128, 256, 0, stream>>>(adjb, nullptr, 512, Yth, Ytl, nullptr, dinv,
                                                 Hbh, Hbl, nullptr, 0);
    k_mfg<128, false, 0><<<128, 256, 0, stream>>>(Hbh, Hbl, ATT, gwt1h, gwt1l, gb1, dinv,
                                                  Yth, Ytl, nullptr, 0);
    k_mfg<512, true, 1><<<128, 256, 0, stream>>>(adjb, nullptr, 512, Yth, Ytl, nullptr, dinv,
                                                 Hbh, Hbl, nullptr, 128);
    k_mfg<128, false, 0><<<128, 256, 0, stream>>>(Hbh + 128, Hbl + 128, ATT, gwt2h, gwt2l, gb2, dinv,
                                                  Yth, Ytl, nullptr, 0);
    k_mfg<512, true, 1><<<128, 256, 0, stream>>>(adjb, nullptr, 512, Yth, Ytl, nullptr, dinv,
                                                 Hbh, Hbl, nullptr, 256);

    k_mfg<384, false, 2><<<dim3(128, 3), 256, 0, stream>>>(Hbh, Hbl, ATT, aw1th, aw1tl, ab1, nullptr,
                                                           nullptr, nullptr, P, 0);
    k_attn2<<<NB * NN / 32, 256, 0, stream>>>(P, aw2, ab2, logit);
    k_attnsm<<<NB, 512, 0, stream>>>(logit, maskp);
    k_scaleHb<<<NB * NN * ATT / 256, 256, 0, stream>>>(Hbh, Hbl, logit, numn);

    hipMemsetAsync(bij, 0, (size_t)NB * NN * 96 * sizeof(float), stream);
    for (int it = 0; it < 3; it++) {
        k_sm16<<<NB * NN * 96 / 256, 256, 0, stream>>>(bij, cij);
        k_Gs<<<NB * 24, 256, 0, stream>>>(cij, Hbh, Hbl, Gs);
        k_SV<<<NB, 512, 0, stream>>>(Gs, Wg, numn, vg);
        if (it < 2) {
            k_Wv<<<NB, 256, 0, stream>>>(vg, Wg, Wv);
            k_bup<<<NB * 16, 256, 0, stream>>>(Hbh, Hbl, Wv, bij);
        }
    }

    k_caps2<<<NB, 256, 0, stream>>>(vg, Wc, label, recon, rw1, rb1, rw2, rb2, out, marg, recl);
    k_final<<<1, 64, 0, stream>>>(marg, recl, out);
}

// Round 5
// 548.165 us; speedup vs baseline: 1.6394x; 1.0452x over previous
//
#include <hip/hip_runtime.h>
#include <hip/hip_bf16.h>
#include <math.h>

#define NB 32
#define NN 512
#define GIN 192
#define ATT 384
#define EPSF 1e-11f

typedef __attribute__((ext_vector_type(4))) float f32x4;
typedef __attribute__((ext_vector_type(8))) short short8;

__device__ __forceinline__ ushort bfhi(float f) {
    uint u = __float_as_uint(f);
    return (ushort)((u + 0x7FFFu + ((u >> 16) & 1u)) >> 16);
}
__device__ __forceinline__ float bff(ushort h) {
    return __uint_as_float(((uint)h) << 16);
}
__device__ __forceinline__ void bfsplit(float f, ushort& hi, ushort& lo) {
    hi = bfhi(f);
    lo = bfhi(f - bff(hi));
}

// ------- fused: adj fp32 -> bf16, plus row sum (dinv) and row max (mask) -------
__global__ __launch_bounds__(128) void k_prep(const float* __restrict__ adj,
                                              ushort* __restrict__ adjb,
                                              float* __restrict__ dinv,
                                              float* __restrict__ mask) {
    int row = blockIdx.x;  // b*n
    int t = threadIdx.x;   // 128
    const float* a = adj + (size_t)row * NN;
    float4 v = ((const float4*)a)[t];
    ushort4 u;
    u.x = bfhi(v.x); u.y = bfhi(v.y); u.z = bfhi(v.z); u.w = bfhi(v.w);
    ((ushort4*)(adjb + (size_t)row * NN))[t] = u;
    float s = v.x + v.y + v.z + v.w;
    float m = fmaxf(fmaxf(v.x, v.y), fmaxf(v.z, v.w));
    for (int off = 32; off; off >>= 1) {
        s += __shfl_xor(s, off);
        m = fmaxf(m, __shfl_xor(m, off));
    }
    __shared__ float ss[2], mm[2];
    if ((t & 63) == 0) { ss[t >> 6] = s; mm[t >> 6] = m; }
    __syncthreads();
    if (t == 0) {
        float S = ss[0] + ss[1];
        dinv[row] = S > 0.f ? 1.0f / sqrtf(S) : 0.f;
        mask[row] = fmaxf(mm[0], mm[1]);
    }
}

// ---------------- embedding gather -> split bf16 planes ----------------
__global__ void k_gather(const int* __restrict__ n0, const int* __restrict__ n1,
                         const int* __restrict__ n2, const float* __restrict__ e0,
                         const float* __restrict__ e1, const float* __restrict__ e2,
                         ushort* __restrict__ fh, ushort* __restrict__ fl) {
    int tid = blockIdx.x * 256 + threadIdx.x;
    if (tid >= NB * NN * GIN) return;
    int bn = tid / GIN, f = tid - bn * GIN;
    float v;
    if (f < 64)       v = e0[n0[bn] * 64 + f];
    else if (f < 128) v = e1[n1[bn] * 64 + (f - 64)];
    else              v = e2[n2[bn] * 64 + (f - 128)];
    ushort h, lo;
    bfsplit(v, h, lo);
    fh[tid] = h; fl[tid] = lo;
}

// ------- all weight transposes in one launch: W [K][N] -> Wt [N][K] split bf16 -------
__global__ __launch_bounds__(256) void k_twtall(
    const float* __restrict__ gw0, const float* __restrict__ gw1,
    const float* __restrict__ gw2, const float* __restrict__ aw1,
    ushort* __restrict__ t0h, ushort* __restrict__ t0l,
    ushort* __restrict__ t1h, ushort* __restrict__ t1l,
    ushort* __restrict__ t2h, ushort* __restrict__ t2l,
    ushort* __restrict__ tah, ushort* __restrict__ tal) {
    const float* W; ushort *Th, *Tl; int K, N;
    switch (blockIdx.z) {
        case 0: W = gw0; Th = t0h; Tl = t0l; K = 192; N = 128; break;
        case 1: W = gw1; Th = t1h; Tl = t1l; K = 128; N = 128; break;
        case 2: W = gw2; Th = t2h; Tl = t2l; K = 128; N = 128; break;
        default: W = aw1; Th = tah; Tl = tal; K = 384; N = 384; break;
    }
    int k0 = blockIdx.x * 32, n0 = blockIdx.y * 32;
    if (k0 >= K || n0 >= N) return;
    __shared__ float tile[32][33];
    int t = threadIdx.x, tx = t & 31, ty = t >> 5;
#pragma unroll
    for (int r = 0; r < 4; r++)
        tile[ty + r * 8][tx] = W[(size_t)(k0 + ty + r * 8) * N + n0 + tx];
    __syncthreads();
#pragma unroll
    for (int r = 0; r < 4; r++) {
        int nn = ty + r * 8;
        float v = tile[tx][nn];
        ushort h, lo;
        bfsplit(v, h, lo);
        size_t o = (size_t)(n0 + nn) * K + k0 + tx;
        Th[o] = h; Tl[o] = lo;
    }
}

// ================= MFMA split-bf16 GEMM =================
// EPI 0: Yt = (acc + bias[c]) * dinv[r] -> transposed bf16 planes per batch
// EPI 1: Hb = tanh(acc * dinv[r]) -> bf16 planes at col hoff+c (B += batch panel)
// EPI 3: atomicAdd(logit[r], sum_c tanh(acc+bias[c])*aw2[c])
template <int KK, bool AEX, int EPI>
__global__ __launch_bounds__(256) void k_mfg(
    const ushort* __restrict__ Ah, const ushort* __restrict__ Al, int lda,
    const ushort* __restrict__ Bh, const ushort* __restrict__ Bl,
    const float* __restrict__ bias, const float* __restrict__ dinv,
    ushort* __restrict__ O1, ushort* __restrict__ O2, float* __restrict__ Of,
    const float* __restrict__ aw2p, int hoff) {
    __shared__ ushort Ash[4096], Asl[4096], Bsh[4096], Bsl[4096];
    int t = threadIdx.x;
    int m0 = blockIdx.x * 128;
    int n0 = blockIdx.y * 128;
    if constexpr (EPI == 1) {
        size_t off = (size_t)(m0 >> 9) * 128 * 512;
        Bh += off; Bl += off;
    }
    int l = t & 63, w = t >> 6, wr = w >> 1, wc = w & 1;
    f32x4 z = {0.f, 0.f, 0.f, 0.f};
    f32x4 acc[4][4];
#pragma unroll
    for (int i = 0; i < 4; i++)
#pragma unroll
        for (int j = 0; j < 4; j++) acc[i][j] = z;

    for (int k0 = 0; k0 < KK; k0 += 32) {
        if (k0) __syncthreads();
#pragma unroll
        for (int f = 0; f < 2; f++) {
            int fi = t + f * 256;
            int ll = fi & 63, g16 = fi >> 6;
            int rowA = m0 + g16 * 16 + (ll & 15);
            int rowB = n0 + g16 * 16 + (ll & 15);
            int ko = k0 + (ll >> 4) * 8;
            *(short8*)&Ash[fi * 8] = *(const short8*)&Ah[(size_t)rowA * lda + ko];
            if constexpr (!AEX)
                *(short8*)&Asl[fi * 8] = *(const short8*)&Al[(size_t)rowA * lda + ko];
            *(short8*)&Bsh[fi * 8] = *(const short8*)&Bh[(size_t)rowB * KK + ko];
            *(short8*)&Bsl[fi * 8] = *(const short8*)&Bl[(size_t)rowB * KK + ko];
        }
        __syncthreads();
        short8 ah[4], al[4], bh[4], bl[4];
#pragma unroll
        for (int i = 0; i < 4; i++) {
            ah[i] = *(const short8*)&Ash[((wr * 4 + i) * 64 + l) * 8];
            if constexpr (!AEX) al[i] = *(const short8*)&Asl[((wr * 4 + i) * 64 + l) * 8];
        }
#pragma unroll
        for (int j = 0; j < 4; j++) {
            bh[j] = *(const short8*)&Bsh[((wc * 4 + j) * 64 + l) * 8];
            bl[j] = *(const short8*)&Bsl[((wc * 4 + j) * 64 + l) * 8];
        }
#pragma unroll
        for (int i = 0; i < 4; i++)
#pragma unroll
            for (int j = 0; j < 4; j++) {
                acc[i][j] = __builtin_amdgcn_mfma_f32_16x16x32_bf16(ah[i], bh[j], acc[i][j], 0, 0, 0);
                acc[i][j] = __builtin_amdgcn_mfma_f32_16x16x32_bf16(ah[i], bl[j], acc[i][j], 0, 0, 0);
                if constexpr (!AEX)
                    acc[i][j] = __builtin_amdgcn_mfma_f32_16x16x32_bf16(al[i], bh[j], acc[i][j], 0, 0, 0);
            }
    }
    // epilogue
    if constexpr (EPI == 3) {
#pragma unroll
        for (int i = 0; i < 4; i++) {
            float rs[4] = {0.f, 0.f, 0.f, 0.f};
#pragma unroll
            for (int j = 0; j < 4; j++) {
                int gc = n0 + (wc * 4 + j) * 16 + (l & 15);
                float bv = bias[gc], wv = aw2p[gc];
#pragma unroll
                for (int r = 0; r < 4; r++)
                    rs[r] += tanhf(acc[i][j][r] + bv) * wv;
            }
#pragma unroll
            for (int r = 0; r < 4; r++) {
                rs[r] += __shfl_xor(rs[r], 1, 16);
                rs[r] += __shfl_xor(rs[r], 2, 16);
                rs[r] += __shfl_xor(rs[r], 4, 16);
                rs[r] += __shfl_xor(rs[r], 8, 16);
            }
            if ((l & 15) == 0) {
                int gr0 = m0 + (wr * 4 + i) * 16 + 4 * (l >> 4);
#pragma unroll
                for (int r = 0; r < 4; r++) atomicAdd(&Of[gr0 + r], rs[r]);
            }
        }
    } else {
#pragma unroll
        for (int i = 0; i < 4; i++)
#pragma unroll
            for (int j = 0; j < 4; j++) {
                int gc = n0 + (wc * 4 + j) * 16 + (l & 15);
                int gr0 = m0 + (wr * 4 + i) * 16 + 4 * (l >> 4);
                if constexpr (EPI == 0) {
                    float bv = bias[gc];
                    size_t ob = (size_t)(m0 >> 9) * 65536 + (size_t)gc * 512 + (gr0 & 511);
#pragma unroll
                    for (int r = 0; r < 4; r++) {
                        float v = (acc[i][j][r] + bv) * dinv[gr0 + r];
                        ushort h, lo;
                        bfsplit(v, h, lo);
                        O1[ob + r] = h; O2[ob + r] = lo;
                    }
                } else {
#pragma unroll
                    for (int r = 0; r < 4; r++) {
                        float v = tanhf(acc[i][j][r] * dinv[gr0 + r]);
                        ushort h, lo;
                        bfsplit(v, h, lo);
                        size_t o = (size_t)(gr0 + r) * ATT + hoff + gc;
                        O1[o] = h; O2[o] = lo;
                    }
                }
            }
    }
}

// ------- attention softmax + numn + scale = attn*numn (in-place into logit) -------
__global__ __launch_bounds__(512) void k_attnsm(float* __restrict__ logit,
                                                const float* __restrict__ mask,
                                                float* __restrict__ numn) {
    __shared__ float red[8], red2[8], red3[8];
    int b = blockIdx.x, t = threadIdx.x;
    float mk = mask[b * NN + t];
    float x = mk > 0.f ? logit[b * NN + t] : -INFINITY;
    float m = x, nsum = mk;
    for (int off = 32; off; off >>= 1) {
        m = fmaxf(m, __shfl_xor(m, off));
        nsum += __shfl_xor(nsum, off);
    }
    if ((t & 63) == 0) { red[t >> 6] = m; red3[t >> 6] = nsum; }
    __syncthreads();
    float gm = red[0], nn = red3[0];
    for (int i = 1; i < 8; i++) { gm = fmaxf(gm, red[i]); nn += red3[i]; }
    float e = expf(x - gm);
    float s = e;
    for (int off = 32; off; off >>= 1) s += __shfl_xor(s, off);
    if ((t & 63) == 0) red2[t >> 6] = s;
    __syncthreads();
    float gs = 0.f;
    for (int i = 0; i < 8; i++) gs += red2[i];
    logit[b * NN + t] = (e / gs) * nn;
    if (t == 0) numn[b] = nn;
}

// ------- iter-0: Hsum[b,c,i] = sum_n scale[b,n]*H[b,n,c,i] -------
__global__ __launch_bounds__(256) void k_Hsum(const ushort* __restrict__ Hh,
                                              const ushort* __restrict__ Hl,
                                              const float* __restrict__ scale,
                                              float* __restrict__ G0) {
    int blk = blockIdx.x;  // b*6 + c
    int c = blk % 6, b = blk / 6;
    int t = threadIdx.x;
    int i = t & 63, g = t >> 6;
    float s = 0.f;
    for (int n = g * 128; n < g * 128 + 128; n++) {
        size_t o = ((size_t)b * NN + n) * ATT + c * 64 + i;
        s += scale[b * NN + n] * (bff(Hh[o]) + bff(Hl[o]));
    }
    __shared__ float red[256];
    red[t] = s;
    __syncthreads();
    if (t < 128) red[t] += red[t + 128];
    __syncthreads();
    if (t < 64) G0[(size_t)blk * 64 + i] = red[t] + red[t + 64];
}

// ------- iter-0 SV (c=1/16) + Wv fused -------
__global__ __launch_bounds__(512) void k_SV0(const float* __restrict__ G0,
                                             const float* __restrict__ Wg,
                                             const float* __restrict__ numn,
                                             float* __restrict__ vg,
                                             float* __restrict__ Wv) {
    __shared__ float gl[384];
    __shared__ float vvs[512];
    int b = blockIdx.x, t = threadIdx.x;
    if (t < 384) gl[t] = G0[b * 384 + t];
    __syncthreads();
    int j = t >> 5, d = t & 31;
    float s = 0.f;
    for (int ci = 0; ci < 384; ci++) s += gl[ci] * Wg[((size_t)ci * 16 + j) * 32 + d];
    s *= (1.f / 16.f) / numn[b];
    float sq = s * s;
    for (int off = 16; off; off >>= 1) sq += __shfl_xor(sq, off, 32);
    float v = (sq / (1.f + sq)) * s / sqrtf(sq + EPSF);
    vvs[t] = v;
    vg[(size_t)b * 512 + t] = v;
    __syncthreads();
    for (int idx = t; idx < 6144; idx += 512) {
        int c = idx >> 10, r = idx & 1023, i = r >> 4, jj = r & 15;
        float a = 0.f;
        const float* w = Wg + (((size_t)c * 64 + i) * 16 + jj) * 32;
        for (int d2 = 0; d2 < 32; d2++) a += w[d2] * vvs[jj * 32 + d2];
        Wv[(size_t)b * 6144 + idx] = a;
    }
}

// ------- Gs with inline softmax over bij (scaled H) -------
__global__ __launch_bounds__(256) void k_GsSM(const float* __restrict__ bij,
                                              const ushort* __restrict__ Hh,
                                              const ushort* __restrict__ Hl,
                                              const float* __restrict__ scale,
                                              float* __restrict__ Gs) {
    int blk = blockIdx.x;  // b*24 + c*4 + seg
    int seg = blk & 3, c = (blk >> 2) % 6, b = blk / 24;
    __shared__ float ct[16 * 16];
    __shared__ float ht[16 * 64];
    int t = threadIdx.x;
    int i = t & 63, j0 = t >> 6;
    float acc[4] = {0.f, 0.f, 0.f, 0.f};
    int n0 = seg * 128;
    for (int nc = 0; nc < 128; nc += 16) {
        {
            int nn = t >> 4;  // jj = t&15, 16 lanes per row
            float v = bij[(((size_t)b * NN + n0 + nc + nn) * 6 + c) * 16 + (t & 15)];
            float mx = v;
            mx = fmaxf(mx, __shfl_xor(mx, 1, 16));
            mx = fmaxf(mx, __shfl_xor(mx, 2, 16));
            mx = fmaxf(mx, __shfl_xor(mx, 4, 16));
            mx = fmaxf(mx, __shfl_xor(mx, 8, 16));
            float e = expf(v - mx);
            float sm = e;
            sm += __shfl_xor(sm, 1, 16);
            sm += __shfl_xor(sm, 2, 16);
            sm += __shfl_xor(sm, 4, 16);
            sm += __shfl_xor(sm, 8, 16);
            ct[t] = e / sm;
        }
        for (int idx = t; idx < 1024; idx += 256) {
            int nn = idx >> 6, ii = idx & 63;
            int n = n0 + nc + nn;
            size_t o = ((size_t)b * NN + n) * ATT + c * 64 + ii;
            ht[idx] = scale[b * NN + n] * (bff(Hh[o]) + bff(Hl[o]));
        }
        __syncthreads();
        for (int nn = 0; nn < 16; nn++) {
            float hv = ht[nn * 64 + i];
#pragma unroll
            for (int q = 0; q < 4; q++) acc[q] += ct[nn * 16 + j0 * 4 + q] * hv;
        }
        __syncthreads();
    }
#pragma unroll
    for (int q = 0; q < 4; q++) {
        int j = j0 * 4 + q;
        Gs[(((size_t)b * 6 + c) * 4 + seg) * 1024 + j * 64 + i] = acc[q];
    }
}

// ------- SV (+optional Wv) for iters 1,2 -------
template <bool DOWV>
__global__ __launch_bounds__(512) void k_SVWv(const float* __restrict__ Gs,
                                              const float* __restrict__ Wg,
                                              const float* __restrict__ numn,
                                              float* __restrict__ vg,
                                              float* __restrict__ Wv) {
    __shared__ float gsum[6144];
    __shared__ float vvs[512];
    int b = blockIdx.x, t = threadIdx.x;
    for (int idx = t; idx < 6144; idx += 512) {
        int c = idx >> 10, r = idx & 1023;
        const float* g = Gs + ((size_t)b * 6 + c) * 4096 + r;
        gsum[idx] = g[0] + g[1024] + g[2048] + g[3072];
    }
    __syncthreads();
    int j = t >> 5, d = t & 31;
    float s = 0.f;
    for (int c = 0; c < 6; c++)
        for (int i2 = 0; i2 < 64; i2++)
            s += gsum[(c * 16 + j) * 64 + i2] * Wg[(((size_t)c * 64 + i2) * 16 + j) * 32 + d];
    s /= numn[b];
    float sq = s * s;
    for (int off = 16; off; off >>= 1) sq += __shfl_xor(sq, off, 32);
    float v = (sq / (1.f + sq)) * s / sqrtf(sq + EPSF);
    vg[(size_t)b * 512 + t] = v;
    if constexpr (DOWV) {
        vvs[t] = v;
        __syncthreads();
        for (int idx = t; idx < 6144; idx += 512) {
            int c = idx >> 10, r = idx & 1023, i = r >> 4, jj = r & 15;
            float a = 0.f;
            const float* w = Wg + (((size_t)c * 64 + i) * 16 + jj) * 32;
            for (int d2 = 0; d2 < 32; d2++) a += w[d2] * vvs[jj * 32 + d2];
            Wv[(size_t)b * 6144 + idx] = a;
        }
    }
}

// ------- b_ij (=|+=) sum_i scale*H[b,n,c,i]*Wv[b,c,i,j] -------
template <bool ACC>
__global__ __launch_bounds__(256) void k_bup(const ushort* __restrict__ Hh,
                                             const ushort* __restrict__ Hl,
                                             const float* __restrict__ scale,
                                             const float* __restrict__ Wv,
                                             float* __restrict__ bij) {
    int blk = blockIdx.x;
    int b = blk >> 4;
    int n0 = (blk & 15) * 32;
    __shared__ float wl[6144];
    __shared__ float hl[32 * ATT];
    int t = threadIdx.x;
    for (int idx = t; idx < 6144; idx += 256) wl[idx] = Wv[(size_t)b * 6144 + idx];
    for (int idx = t; idx < 32 * ATT; idx += 256) {
        int nn = idx / ATT;
        size_t o = ((size_t)b * NN + n0) * ATT + idx;
        hl[idx] = scale[b * NN + n0 + nn] * (bff(Hh[o]) + bff(Hl[o]));
    }
    __syncthreads();
    for (int idx = t; idx < 3072; idx += 256) {
        int nn = idx / 96, r = idx % 96, c = r >> 4, j = r & 15;
        float a = 0.f;
        const float* h = hl + nn * ATT + c * 64;
        const float* w = wl + c * 1024 + j;
#pragma unroll
        for (int i2 = 0; i2 < 64; i2++) a += h[i2] * w[i2 * 16];
        size_t o = (((size_t)b * NN + n0 + nn) * 6 + c) * 16 + j;
        if constexpr (ACC) bij[o] += a;
        else bij[o] = a;
    }
}

// ---------------- second routing + losses, one block per batch ----------------
__global__ __launch_bounds__(256) void k_caps2(
    const float* __restrict__ vg, const float* __restrict__ Wc,
    const int* __restrict__ label, const float* __restrict__ recon_in,
    const float* __restrict__ rw1, const float* __restrict__ rb1,
    const float* __restrict__ rw2, const float* __restrict__ rb2,
    float* __restrict__ out, float* __restrict__ marg, float* __restrict__ reconl) {
    int b = blockIdx.x, t = threadIdx.x;
    __shared__ float vl[512];
    __shared__ float u2[3072];
    __shared__ float b2[96], c2b[96];
    __shared__ float vv[192];
    __shared__ float magl[6];
    __shared__ float cm[32];
    __shared__ float hidl[128];
    __shared__ float red[256];
    vl[t] = vg[(size_t)b * 512 + t];
    vl[t + 256] = vg[(size_t)b * 512 + t + 256];
    if (t < 96) b2[t] = 0.f;
    __syncthreads();
    for (int idx = t; idx < 3072; idx += 256) {
        int c = idx / 192, r = idx - c * 192;  // r = j*32+d
        float a = 0.f;
        const float* w = Wc + (size_t)c * 6144 + r;
        for (int i2 = 0; i2 < 32; i2++) a += vl[c * 32 + i2] * w[i2 * 192];
        u2[idx] = a;
    }
    __syncthreads();
    for (int it = 0; it < 3; it++) {
        if (t < 16) {
            float mx = -INFINITY;
            for (int j = 0; j < 6; j++) mx = fmaxf(mx, b2[t * 6 + j]);
            float e[6], s = 0.f;
            for (int j = 0; j < 6; j++) { e[j] = expf(b2[t * 6 + j] - mx); s += e[j]; }
            for (int j = 0; j < 6; j++) c2b[t * 6 + j] = e[j] / s;
        }
        __syncthreads();
        if (t < 192) {
            int j = t >> 5, d = t & 31;
            float s = 0.f;
            for (int c = 0; c < 16; c++) s += c2b[c * 6 + j] * u2[c * 192 + j * 32 + d];
            float sq = s * s;
            for (int off = 16; off; off >>= 1) sq += __shfl_xor(sq, off, 32);
            vv[t] = (sq / (1.f + sq)) * s / sqrtf(sq + EPSF);
        }
        __syncthreads();
        if (it < 2) {
            if (t < 96) {
                int c = t / 6, j = t - c * 6;
                float a = 0.f;
                for (int d = 0; d < 32; d++) a += u2[c * 192 + j * 32 + d] * vv[j * 32 + d];
                b2[t] += a;
            }
            __syncthreads();
        }
    }
    if (t < 192) out[(size_t)b * 192 + t] = vv[t];
    if (t < 6) {
        float s = 0.f;
        for (int d = 0; d < 32; d++) { float v = vv[t * 32 + d]; s += v * v; }
        magl[t] = sqrtf(s);
    }
    __syncthreads();
    int lab = label[b];
    if (t == 0) {
        float L = 0.f;
        int p = 0;
        float best = magl[0];
        for (int j = 0; j < 6; j++) {
            float mg = magl[j];
            if (mg > best) { best = mg; p = j; }
            float ml = fmaxf(0.9f - mg, 0.f); ml *= ml;
            float mr = fmaxf(mg - 0.1f, 0.f); mr *= mr;
            L += (j == lab) ? ml : 0.5f * mr;
        }
        marg[b] = L;
        out[6147 + b] = (float)p;
    }
    if (t < 32) cm[t] = vv[lab * 32 + t];
    __syncthreads();
    if (t < 128) {
        float a = rb1[t];
        for (int d = 0; d < 32; d++) a += cm[d] * rw1[d * 128 + t];
        hidl[t] = fmaxf(a, 0.f);
    }
    __syncthreads();
    bool act = t < 208;
    float rv = 0.f, rin = 0.f;
    if (act) {
        float a = rb2[t];
        for (int k = 0; k < 128; k++) a += hidl[k] * rw2[k * 208 + t];
        rv = 1.f / (1.f + expf(-a));
        rin = recon_in[(size_t)b * 208 + t];
    }
    red[t] = act ? rin : -INFINITY;
    __syncthreads();
    for (int s2 = 128; s2; s2 >>= 1) {
        if (t < s2) red[t] = fmaxf(red[t], red[t + s2]);
        __syncthreads();
    }
    float rmax = red[0];
    __syncthreads();
    float dpos = 0.f, dneg = 0.f;
    if (act) {
        float rec_val = rin / (rmax + EPSF);
        float d2 = rv - rec_val; d2 *= d2;
        bool neg = rin < 1e-5f;
        dpos = neg ? 0.f : d2;
        dneg = neg ? d2 : 0.f;
    }
    red[t] = dpos;
    __syncthreads();
    for (int s2 = 128; s2; s2 >>= 1) {
        if (t < s2) red[t] = fmaxf(red[t], red[t + s2]);
        __syncthreads();
    }
    float mp = red[0];
    __syncthreads();
    red[t] = dneg;
    __syncthreads();
    for (int s2 = 128; s2; s2 >>= 1) {
        if (t < s2) red[t] = fmaxf(red[t], red[t + s2]);
        __syncthreads();
    }
    if (t == 0) reconl[b] = mp + red[0];
}

__global__ void k_final(const float* __restrict__ marg, const float* __restrict__ reconl,
                        float* __restrict__ out) {
    int t = threadIdx.x;  // 64
    float m = (t < 32) ? marg[t] : 0.f;
    float r = (t < 32) ? reconl[t] : 0.f;
    for (int off = 16; off; off >>= 1) { m += __shfl_xor(m, off, 32); r += __shfl_xor(r, off, 32); }
    if (t == 0) {
        m /= 32.f;
        r /= 32.f;
        out[6144] = m + 0.1f * r;
        out[6145] = m;
        out[6146] = r;
    }
}

extern "C" void kernel_launch(void* const* d_in, const int* in_sizes, int n_in,
                              void* d_out, int out_size, void* d_ws, size_t ws_size,
                              hipStream_t stream) {
    const float* adj   = (const float*)d_in[0];
    const int*   n0    = (const int*)d_in[1];
    const int*   n1    = (const int*)d_in[2];
    const int*   n2    = (const int*)d_in[3];
    const int*   label = (const int*)d_in[4];
    const float* recon = (const float*)d_in[5];
    const float* e0    = (const float*)d_in[6];
    const float* e1    = (const float*)d_in[7];
    const float* e2    = (const float*)d_in[8];
    const float* gw0   = (const float*)d_in[9];
    const float* gb0   = (const float*)d_in[10];
    const float* gw1   = (const float*)d_in[11];
    const float* gb1   = (const float*)d_in[12];
    const float* gw2   = (const float*)d_in[13];
    const float* gb2   = (const float*)d_in[14];
    const float* aw1   = (const float*)d_in[15];
    const float* ab1   = (const float*)d_in[16];
    const float* aw2   = (const float*)d_in[17];
    const float* Wg    = (const float*)d_in[19];
    const float* Wc    = (const float*)d_in[20];
    const float* rw1   = (const float*)d_in[21];
    const float* rb1   = (const float*)d_in[22];
    const float* rw2   = (const float*)d_in[23];
    const float* rb2   = (const float*)d_in[24];
    float* out = (float*)d_out;

    char* p = (char*)d_ws;
    auto alloc = [&](size_t bytes) { char* r = p; p += (bytes + 255) & ~(size_t)255; return r; };
    float*  dinv   = (float*)alloc(NB * NN * 4);
    float*  maskp  = (float*)alloc(NB * NN * 4);
    float*  numn   = (float*)alloc(NB * 4);
    float*  logit  = (float*)alloc(NB * NN * 4);  // later: scale = attn*numn
    float*  bij    = (float*)alloc((size_t)NB * NN * 96 * 4);
    float*  Gs     = (float*)alloc((size_t)NB * 24576 * 4);
    float*  G0     = (float*)alloc(NB * 384 * 4);
    float*  vg     = (float*)alloc(NB * 512 * 4);
    float*  Wv     = (float*)alloc(NB * 6144 * 4);
    float*  marg   = (float*)alloc(NB * 4);
    float*  recl   = (float*)alloc(NB * 4);
    ushort* gwt0h  = (ushort*)alloc(128 * 192 * 2);
    ushort* gwt0l  = (ushort*)alloc(128 * 192 * 2);
    ushort* gwt1h  = (ushort*)alloc(128 * 128 * 2);
    ushort* gwt1l  = (ushort*)alloc(128 * 128 * 2);
    ushort* gwt2h  = (ushort*)alloc(128 * 128 * 2);
    ushort* gwt2l  = (ushort*)alloc(128 * 128 * 2);
    ushort* aw1th  = (ushort*)alloc(384 * 384 * 2);
    ushort* aw1tl  = (ushort*)alloc(384 * 384 * 2);
    ushort* Yth    = (ushort*)alloc((size_t)NB * 128 * 512 * 2);
    ushort* Ytl    = (ushort*)alloc((size_t)NB * 128 * 512 * 2);
    ushort* Hbh    = (ushort*)alloc((size_t)NB * NN * ATT * 2);
    ushort* Hbl    = (ushort*)alloc((size_t)NB * NN * ATT * 2);
    ushort* fbh    = (ushort*)alloc((size_t)NB * NN * GIN * 2);
    ushort* fbl    = (ushort*)alloc((size_t)NB * NN * GIN * 2);
    ushort* adjb   = (ushort*)alloc((size_t)NB * NN * NN * 2);

    k_prep<<<NB * NN, 128, 0, stream>>>(adj, adjb, dinv, maskp);
    k_gather<<<(NB * NN * GIN + 255) / 256, 256, 0, stream>>>(n0, n1, n2, e0, e1, e2, fbh, fbl);
    k_twtall<<<dim3(12, 12, 4), 256, 0, stream>>>(gw0, gw1, gw2, aw1, gwt0h, gwt0l,
                                                  gwt1h, gwt1l, gwt2h, gwt2l, aw1th, aw1tl);

    k_mfg<192, false, 0><<<128, 256, 0, stream>>>(fbh, fbl, 192, gwt0h, gwt0l, gb0, dinv,
                                                  Yth, Ytl, nullptr, nullptr, 0);
    k_mfg<512, true, 1><<<128, 256, 0, stream>>>(adjb, nullptr, 512, Yth, Ytl, nullptr, dinv,
                                                 Hbh, Hbl, nullptr, nullptr, 0);
    k_mfg<128, false, 0><<<128, 256, 0, stream>>>(Hbh, Hbl, ATT, gwt1h, gwt1l, gb1, dinv,
                                                  Yth, Ytl, nullptr, nullptr, 0);
    k_mfg<512, true, 1><<<128, 256, 0, stream>>>(adjb, nullptr, 512, Yth, Ytl, nullptr, dinv,
                                                 Hbh, Hbl, nullptr, nullptr, 128);
    k_mfg<128, false, 0><<<128, 256, 0, stream>>>(Hbh + 128, Hbl + 128, ATT, gwt2h, gwt2l, gb2, dinv,
                                                  Yth, Ytl, nullptr, nullptr, 0);
    k_mfg<512, true, 1><<<128, 256, 0, stream>>>(adjb, nullptr, 512, Yth, Ytl, nullptr, dinv,
                                                 Hbh, Hbl, nullptr, nullptr, 256);

    hipMemsetAsync(logit, 0, NB * NN * sizeof(float), stream);
    k_mfg<384, false, 3><<<dim3(128, 3), 256, 0, stream>>>(Hbh, Hbl, ATT, aw1th, aw1tl, ab1, nullptr,
                                                           nullptr, nullptr, logit, aw2, 0);
    k_attnsm<<<NB, 512, 0, stream>>>(logit, maskp, numn);

    // routing iter 0 (c uniform = 1/16)
    k_Hsum<<<NB * 6, 256, 0, stream>>>(Hbh, Hbl, logit, G0);
    k_SV0<<<NB, 512, 0, stream>>>(G0, Wg, numn, vg, Wv);
    k_bup<false><<<NB * 16, 256, 0, stream>>>(Hbh, Hbl, logit, Wv, bij);
    // iter 1
    k_GsSM<<<NB * 24, 256, 0, stream>>>(bij, Hbh, Hbl, logit, Gs);
    k_SVWv<true><<<NB, 512, 0, stream>>>(Gs, Wg, numn, vg, Wv);
    k_bup<true><<<NB * 16, 256, 0, stream>>>(Hbh, Hbl, logit, Wv, bij);
    // iter 2
    k_GsSM<<<NB * 24, 256, 0, stream>>>(bij, Hbh, Hbl, logit, Gs);
    k_SVWv<false><<<NB, 512, 0, stream>>>(Gs, Wg, numn, vg, nullptr);

    k_caps2<<<NB, 256, 0, stream>>>(vg, Wc, label, recon, rw1, rb1, rw2, rb2, out, marg, recl);
    k_final<<<1, 64, 0, stream>>>(marg, recl, out);
}